// Round 9
// baseline (6376.713 us; speedup 1.0000x reference)
//
#include <hip/hip_runtime.h>
#include <math.h>

#define BB 8
#define TT 1024
#define DM 512
#define ROWS (BB*TT)     // 8192
#define ROWS1 (BB*(TT-1))// 8184
#define GRU_J 8
#define GRU_BLK (BB*64)  // 512 blocks

typedef __attribute__((ext_vector_type(4))) float f32x4;
typedef __attribute__((ext_vector_type(8))) short bf16x8;
typedef __attribute__((ext_vector_type(4))) short bf16x4;

#define GLOAD16(g, l) __builtin_amdgcn_global_load_lds( \
    (const __attribute__((address_space(1))) void*)(g), \
    (__attribute__((address_space(3))) void*)(l), 16, 0, 0)

struct RkArgs {
  const float* delta; float* acc; unsigned short* y16;
  const float* dtrow; const int* srcrow;
  const float* x; unsigned short* hin16;
  float wa, cy;
};

__device__ __forceinline__ float sigm_(float v){ return 1.f/(1.f+expf(-v)); }

__device__ __forceinline__ unsigned short f2bf(float f){
  unsigned u = __float_as_uint(f);
  return (unsigned short)((u + 0x7FFFu + ((u>>16)&1u)) >> 16);
}

// ---------------- fused weight cast (all 10 weights, 1 launch) ----------------
__global__ __launch_bounds__(256) void castall_kernel(
    const float* w0, const float* w1, const float* w2, const float* w3,
    const float* w4, const float* w5, const float* w6, const float* w7,
    const float* w8, const float* w9, unsigned short* __restrict__ o)
{
  int i = blockIdx.x*256 + threadIdx.x;           // in float4 units
  if (i >= 2228224) return;
  const float* src; int off;
  if      (i <   65536){ src=w0; off=0; }
  else if (i <  131072){ src=w1; off=65536; }
  else if (i <  327680){ src=w2; off=131072; }
  else if (i <  720896){ src=w3; off=327680; }
  else if (i <  851968){ src=w4; off=720896; }
  else if (i < 1376256){ src=w5; off=851968; }
  else if (i < 1900544){ src=w6; off=1376256; }
  else if (i < 2097152){ src=w7; off=1900544; }
  else if (i < 2162688){ src=w8; off=2097152; }
  else                 { src=w9; off=2162688; }
  float4 v = ((const float4*)src)[i - off];
  ushort4 u;
  u.x = f2bf(v.x); u.y = f2bf(v.y); u.z = f2bf(v.z); u.w = f2bf(v.w);
  ((ushort4*)o)[i] = u;
}

// ---------------- elementwise ----------------
__global__ __launch_bounds__(256) void delta_kernel(const float* __restrict__ x,
    const float* __restrict__ ts, float* __restrict__ delta,
    unsigned short* __restrict__ delta16,
    float* __restrict__ dtrow, int* __restrict__ srcrow)
{
  size_t i = (size_t)blockIdx.x*256 + threadIdx.x;
  int d = (int)(i & (DM-1));
  int r = (int)(i >> 9);
  int b = r / (TT-1), ii = r % (TT-1);
  float dt = ts[b*TT+ii+1] - ts[b*TT+ii];
  float x1 = x[((size_t)b*TT+ii+1)*DM + d];
  float x0 = x[((size_t)b*TT+ii)*DM + d];
  float v = (x1 - x0) / dt;
  delta[i] = v;
  delta16[i] = f2bf(v);
  if (d == 0) { dtrow[r] = dt; srcrow[r] = b*TT + ii; }
}

// ---------------- LayerNorm (block per row, D=512) ----------------
// TE=1: input = x + time-encoding (fused timeenc, layer-0 ln1); also writes zout f32.
template<int BF, int TE>
__global__ __launch_bounds__(256) void ln_kernel(const float* __restrict__ x,
    const float* __restrict__ w, const float* __restrict__ b,
    void* __restrict__ outp,
    const float* ts, const float* te_a, const float* te_b, float* zout)
{
  int row = blockIdx.x;
  int tid = threadIdx.x;
  const float* xr = x + (size_t)row*DM;
  float2 v = *(const float2*)(xr + tid*2);
  if (TE) {
    float t = ts[row];
    int d0 = tid*2;
    int fi = d0 >> 2;
    float fr = expf(-(float)fi * 0.061606661f) * 1.5707964f;
    float ph = t * fr;
    float tm0 = ((d0 & 3) == 0) ? sinf(ph) : cosf(ph);
    float tm1 = t*te_a[tid] + te_b[tid];
    v.x += tm0; v.y += tm1;
    *(float2*)(zout + (size_t)row*DM + tid*2) = v;
  }
  float s = v.x+v.y, sq = v.x*v.x + v.y*v.y;
  #pragma unroll
  for (int off=1; off<64; off<<=1){ s += __shfl_xor(s,off); sq += __shfl_xor(sq,off); }
  __shared__ float rs[4], rq[4];
  int wid = tid>>6;
  if ((tid&63)==0){ rs[wid]=s; rq[wid]=sq; }
  __syncthreads();
  s = rs[0]+rs[1]+rs[2]+rs[3];
  sq = rq[0]+rq[1]+rq[2]+rq[3];
  float mean = s*(1.f/DM);
  float var = sq*(1.f/DM) - mean*mean;
  float inv = rsqrtf(var + 1e-5f);
  float2 wv = *(const float2*)(w + tid*2);
  float2 bv = *(const float2*)(b + tid*2);
  float ox = (v.x-mean)*inv*wv.x + bv.x;
  float oy = (v.y-mean)*inv*wv.y + bv.y;
  if (BF) {
    ushort2 u; u.x = f2bf(ox); u.y = f2bf(oy);
    *(ushort2*)((unsigned short*)outp + (size_t)row*DM + tid*2) = u;
  } else {
    float2 o; o.x = ox; o.y = oy;
    *(float2*)((float*)outp + (size_t)row*DM + tid*2) = o;
  }
}

// ---------------- bf16 MFMA GEMM, global_load_lds staging ----------------
// Linear LDS [rows][32] bf16 (64B rows, no pad). Staging: width-16 global_load_lds,
// lane l of wave w covers row w*32+j*16+l/4, 16B slot l&3 (LDS dest is linear).
// Frag reads are bank-balanced (8 lanes per 16B group). One barrier per K-iter;
// the pre-barrier vmcnt(0) drains the load queue (m97 structure).
// RKM: 0 none, 1 RK-init, 2 RK-mid, 3 RK-final(states+zero) epilogues (ldc==512).
template<int ACT, int TN, int RKM>
__global__ __launch_bounds__(256) void bgemm_kernel(
    const unsigned short* __restrict__ A16, const unsigned short* __restrict__ Wb,
    const float* __restrict__ bias, const float* res,
    float* C, unsigned short* Cb, int M, int N, int K, int ldc, RkArgs rk)
{
  const int NJ = TN/32;
  __shared__ __align__(16) unsigned short Al[2][128*32];
  __shared__ __align__(16) unsigned short Wl[2][TN*32];
  const int bm = blockIdx.y*128, bn = blockIdx.x*TN;
  const int tid = threadIdx.x;
  const int lane = tid & 63, wv = tid >> 6;
  const int wm = (wv&1)*64, wn = (wv>>1)*(TN/2);
  const int fl = lane & 15, fk = (lane>>4)*8;
  const int srw = lane >> 2;         // row within 16-row group
  const int scl = (lane & 3)*8;      // 16B slot (elems)
  f32x4 acc[4][NJ];
  #pragma unroll
  for (int i=0;i<4;i++)
    #pragma unroll
    for (int j=0;j<NJ;j++) acc[i][j] = (f32x4){0.f,0.f,0.f,0.f};

  const int nk = K >> 5;

  auto stage = [&](int buf, int kt){
    int k0 = kt*32;
    #pragma unroll
    for (int j=0;j<2;j++){
      int r = wv*32 + j*16 + srw;
      GLOAD16(A16 + (size_t)(bm + r)*K + k0 + scl,
              &Al[buf][(wv*32 + j*16)*32]);
    }
    if (TN == 128) {
      #pragma unroll
      for (int j=0;j<2;j++){
        int r = wv*32 + j*16 + srw;
        GLOAD16(Wb + (size_t)(bn + r)*K + k0 + scl,
                &Wl[buf][(wv*32 + j*16)*32]);
      }
    } else {
      int r = wv*16 + srw;
      GLOAD16(Wb + (size_t)(bn + r)*K + k0 + scl,
              &Wl[buf][(wv*16)*32]);
    }
  };

  stage(0, 0);
  int buf = 0;
  for (int kt = 0; kt < nk; ++kt) {
    __syncthreads();                 // drains vmcnt -> buf ready
    if (kt+1 < nk) stage(buf^1, kt+1);
    bf16x8 av[4], wvv[NJ];
    #pragma unroll
    for (int i=0;i<4;i++) av[i] = *(const bf16x8*)&Al[buf][(wm + i*16 + fl)*32 + fk];
    #pragma unroll
    for (int j=0;j<NJ;j++) wvv[j] = *(const bf16x8*)&Wl[buf][(wn + j*16 + fl)*32 + fk];
    #pragma unroll
    for (int i=0;i<4;i++)
      #pragma unroll
      for (int j=0;j<NJ;j++)
        acc[i][j] = __builtin_amdgcn_mfma_f32_16x16x32_bf16(av[i], wvv[j], acc[i][j], 0, 0, 0);
    buf ^= 1;
  }

  // epilogue: C/D layout col=lane&15, row=(lane>>4)*4+reg
  #pragma unroll
  for (int j=0;j<NJ;j++){
    int gn = bn + wn + j*16 + fl;
    float bv = bias[gn];
    #pragma unroll
    for (int i=0;i<4;i++){
      #pragma unroll
      for (int r=0;r<4;r++){
        int gm = bm + wm + i*16 + (lane>>4)*4 + r;
        if (gm >= M) continue;
        float v = acc[i][j][r] + bv;
        if (ACT==1) v = fmaxf(v, 0.f);
        if (ACT==2) v = tanhf(v);
        if (RKM == 0) {
          if (res) v += res[(size_t)gm*ldc + gn];
          if (C)  C[(size_t)gm*ldc + gn] = v;
          if (Cb) Cb[(size_t)gm*ldc + gn] = f2bf(v);
        } else {
          size_t idx = (size_t)gm*512 + gn;
          float dt = rk.dtrow[gm];
          if (RKM == 1) {
            rk.acc[idx] = v;
            rk.y16[idx] = f2bf(rk.delta[idx] + rk.cy*dt*v);
          } else if (RKM == 2) {
            rk.acc[idx] += rk.wa*v;
            rk.y16[idx] = f2bf(rk.delta[idx] + rk.cy*dt*v);
          } else {
            float a = rk.acc[idx] + v;
            int srow = rk.srcrow[gm];
            rk.hin16[((size_t)srow+1)*512 + gn] =
                f2bf(rk.x[(size_t)srow*512 + gn] + dt*(1.f/6.f)*a);
            if ((srow & (TT-1)) == 0)            // fused zero of t=0 row (after-RK safe)
              rk.hin16[(size_t)srow*512 + gn] = 0;
          }
        }
      }
    }
  }
}

// ---------------- MFMA flash attention ----------------
template<int CAUSAL>
__global__ __launch_bounds__(256) void mattn_kernel(
    const unsigned short* __restrict__ QKV, unsigned short* __restrict__ O)
{
  __shared__ __align__(16) unsigned short Kl[32][72];
  __shared__ __align__(16) unsigned short Vt[64][36];
  __shared__ __align__(16) unsigned short Pl[4][16][40];
  const int b = blockIdx.x >> 3, h = blockIdx.x & 7;
  const int q0 = blockIdx.y * 64;
  const int tid = threadIdx.x;
  const int lane = tid & 63, wid = tid >> 6;
  const int lq = lane & 15, g = lane >> 4;
  const size_t rowbase = (size_t)b*TT;

  bf16x8 qf0, qf1;
  {
    const unsigned short* qp = QKV + (rowbase + q0 + wid*16 + lq)*1536 + h*64 + g*8;
    qf0 = *(const bf16x8*)qp;
    qf1 = *(const bf16x8*)(qp + 32);
  }
  f32x4 o[4];
  #pragma unroll
  for (int dt=0; dt<4; dt++) o[dt] = (f32x4){0.f,0.f,0.f,0.f};
  float mr[4] = {-1e30f,-1e30f,-1e30f,-1e30f};
  float Lr[4] = {0.f,0.f,0.f,0.f};

  const int nkt = CAUSAL ? (q0/32 + 2) : (TT/32);
  const int qwmax = q0 + wid*16 + 15;
  const int sr = tid >> 3, scol = (tid & 7) * 8;

  for (int kt = 0; kt < nkt; ++kt) {
    const int k0 = kt*32;
    __syncthreads();
    *(uint4*)&Kl[sr][scol] = *(const uint4*)(QKV + (rowbase + k0 + sr)*1536 + 512 + h*64 + scol);
    {
      uint4 vv = *(const uint4*)(QKV + (rowbase + k0 + sr)*1536 + 1024 + h*64 + scol);
      const unsigned short* vs = (const unsigned short*)&vv;
      #pragma unroll
      for (int i=0;i<8;i++) Vt[scol+i][sr] = vs[i];
    }
    __syncthreads();
    if (CAUSAL && k0 > qwmax) continue;

    f32x4 st0 = (f32x4){0.f,0.f,0.f,0.f}, st1 = (f32x4){0.f,0.f,0.f,0.f};
    {
      bf16x8 kb;
      kb = *(const bf16x8*)&Kl[lq][g*8];
      st0 = __builtin_amdgcn_mfma_f32_16x16x32_bf16(qf0, kb, st0, 0,0,0);
      kb = *(const bf16x8*)&Kl[lq][g*8+32];
      st0 = __builtin_amdgcn_mfma_f32_16x16x32_bf16(qf1, kb, st0, 0,0,0);
      kb = *(const bf16x8*)&Kl[16+lq][g*8];
      st1 = __builtin_amdgcn_mfma_f32_16x16x32_bf16(qf0, kb, st1, 0,0,0);
      kb = *(const bf16x8*)&Kl[16+lq][g*8+32];
      st1 = __builtin_amdgcn_mfma_f32_16x16x32_bf16(qf1, kb, st1, 0,0,0);
    }
    float s0[4], s1[4];
    #pragma unroll
    for (int r=0;r<4;r++){ s0[r] = st0[r]*0.125f; s1[r] = st1[r]*0.125f; }
    if (CAUSAL) {
      int kg0 = k0 + lq, kg1 = k0 + 16 + lq;
      #pragma unroll
      for (int r=0;r<4;r++){
        int qg = q0 + wid*16 + 4*g + r;
        if (kg0 > qg) s0[r] = -1e30f;
        if (kg1 > qg) s1[r] = -1e30f;
      }
    }
    #pragma unroll
    for (int r=0;r<4;r++){
      float v = fmaxf(s0[r], s1[r]);
      v = fmaxf(v, __shfl_xor(v,1));
      v = fmaxf(v, __shfl_xor(v,2));
      v = fmaxf(v, __shfl_xor(v,4));
      v = fmaxf(v, __shfl_xor(v,8));
      float mn = fmaxf(mr[r], v);
      float scl = expf(mr[r] - mn);
      mr[r] = mn;
      float p0 = expf(s0[r] - mn);
      float p1 = expf(s1[r] - mn);
      float lt = p0 + p1;
      lt += __shfl_xor(lt,1); lt += __shfl_xor(lt,2);
      lt += __shfl_xor(lt,4); lt += __shfl_xor(lt,8);
      Lr[r] = Lr[r]*scl + lt;
      o[0][r] *= scl; o[1][r] *= scl; o[2][r] *= scl; o[3][r] *= scl;
      Pl[wid][4*g+r][lq]    = f2bf(p0);
      Pl[wid][4*g+r][16+lq] = f2bf(p1);
    }
    bf16x8 ap = *(const bf16x8*)&Pl[wid][lq][g*8];
    #pragma unroll
    for (int dt=0; dt<4; dt++){
      bf16x4 a4 = *(const bf16x4*)&Vt[lq+16*dt][g*8];
      bf16x4 b4 = *(const bf16x4*)&Vt[lq+16*dt][g*8+4];
      bf16x8 vb = __builtin_shufflevector(a4, b4, 0,1,2,3,4,5,6,7);
      o[dt] = __builtin_amdgcn_mfma_f32_16x16x32_bf16(ap, vb, o[dt], 0,0,0);
    }
  }

  #pragma unroll
  for (int r=0;r<4;r++){
    float inv = 1.f / Lr[r];
    int qg = q0 + wid*16 + 4*g + r;
    unsigned short* op = O + (rowbase + qg)*DM + h*64 + lq;
    op[0]  = f2bf(o[0][r]*inv);
    op[16] = f2bf(o[1][r]*inv);
    op[32] = f2bf(o[2][r]*inv);
    op[48] = f2bf(o[3][r]*inv);
  }
}

// ---------------- GRU scan v5: per-slice flags, low poll traffic ----------------
// Writers store plain f32 h-words (relaxed agent atomics), every wave drains
// vmcnt(0), barrier, then ONE flag store per slice. Readers: wave0 polls the 64
// flags (256B/iter, 16x less poll traffic than tagged words), then loads h once.
__global__ __launch_bounds__(256) void gru_scan_kernel(
    const float* __restrict__ gx,
    const float* __restrict__ whh,
    const float* __restrict__ bhh,
    float* __restrict__ Hs,
    unsigned short* __restrict__ Hsb,
    float* hbuf,                    // [2][BB][512] f32
    int* flags)                     // [BB][64], memset 0 per launch
{
  __shared__ float wlds[3][GRU_J][512];
  __shared__ float hsp[512];
  const int blk = blockIdx.x;
  const int b = blk & 7;
  const int g = blk >> 3;
  const int j0 = g * GRU_J;
  const int tid = threadIdx.x;
  const int lane = tid & 63, wv = tid >> 6;

  for (int idx = tid; idx < 3*GRU_J*512/4; idx += 256) {
    int f = idx*4;
    int gate = f >> 12;
    int rem = f & 4095;
    int jj = rem >> 9, k = rem & 511;
    *(float4*)&wlds[gate][jj][k] = *(const float4*)&whh[(size_t)(gate*512 + j0 + jj)*512 + k];
  }
  const int row = tid >> 5;
  const int kl = tid & 31;
  const bool fin = (kl == 0);
  float bh0=0.f, bh1=0.f, bh2=0.f;
  if (fin) { bh0 = bhh[j0+row]; bh1 = bhh[512+j0+row]; bh2 = bhh[1024+j0+row]; }
  __syncthreads();

  for (int t = 0; t < TT; t++) {
    float g0=0.f, g1=0.f, g2=0.f;
    if (fin) {   // issued before poll; latency hides under the wait
      const float* gxr = gx + ((size_t)b*TT + t)*1536 + j0 + row;
      g0 = gxr[0]; g1 = gxr[512]; g2 = gxr[1024];
    }
    if (t == 0) {
      hsp[tid] = 0.f; hsp[tid+256] = 0.f;
    } else {
      if (wv == 0) {
        for (;;) {
          int f = __hip_atomic_load(&flags[b*64 + lane],
                                    __ATOMIC_RELAXED, __HIP_MEMORY_SCOPE_AGENT);
          if (__all(f >= t)) break;
          __builtin_amdgcn_s_sleep(1);
        }
      }
      __syncthreads();
      const float* src = hbuf + (((t-1)&1)*BB + b)*512;
      hsp[tid]     = __hip_atomic_load(src + tid,       __ATOMIC_RELAXED, __HIP_MEMORY_SCOPE_AGENT);
      hsp[tid+256] = __hip_atomic_load(src + tid + 256, __ATOMIC_RELAXED, __HIP_MEMORY_SCOPE_AGENT);
    }
    __syncthreads();

    float s0=0.f, s1=0.f, s2=0.f;
    #pragma unroll
    for (int j=0;j<4;j++){
      int k = kl*4 + j*128;
      float4 h4 = *(const float4*)&hsp[k];
      float4 a = *(const float4*)&wlds[0][row][k];
      float4 c = *(const float4*)&wlds[1][row][k];
      float4 d = *(const float4*)&wlds[2][row][k];
      s0 += a.x*h4.x + a.y*h4.y + a.z*h4.z + a.w*h4.w;
      s1 += c.x*h4.x + c.y*h4.y + c.z*h4.z + c.w*h4.w;
      s2 += d.x*h4.x + d.y*h4.y + d.z*h4.z + d.w*h4.w;
    }
    #pragma unroll
    for (int off=1; off<32; off<<=1) {
      s0 += __shfl_xor(s0, off);
      s1 += __shfl_xor(s1, off);
      s2 += __shfl_xor(s2, off);
    }
    float hnew = 0.f;
    if (fin) {
      float r  = sigm_(g0 + s0 + bh0);
      float z  = sigm_(g1 + s1 + bh1);
      float n  = tanhf(g2 + r*(s2 + bh2));
      float hold = hsp[j0 + row];
      hnew = (1.f - z)*n + z*hold;
      __hip_atomic_store(&hbuf[((t&1)*BB + b)*512 + j0 + row], hnew,
                         __ATOMIC_RELAXED, __HIP_MEMORY_SCOPE_AGENT);
    }
    // every wave drains its own h stores; barrier orders all before the flag
    asm volatile("s_waitcnt vmcnt(0)" ::: "memory");
    __syncthreads();
    if (tid == 0)
      __hip_atomic_store(&flags[b*64 + g], t+1,
                         __ATOMIC_RELAXED, __HIP_MEMORY_SCOPE_AGENT);
    if (fin) {   // off the critical path: drained by NEXT step's vmcnt
      size_t off = ((size_t)b*TT + t)*DM + j0 + row;
      Hs[off]  = hnew;
      Hsb[off] = f2bf(hnew);
    }
  }
}

// ---------------- host ----------------
static RkArgs g_norm = {};

static void launch_bgemm(int act, int tn, const unsigned short* A16, const unsigned short* Wb,
                         const float* bias, const float* res, float* C, unsigned short* Cb,
                         int M, int N, int K, int ldc, hipStream_t stream)
{
  dim3 blk(256);
  if (tn == 128) {
    dim3 grid(N/128, (M+127)/128);
    switch(act){
      case 1: bgemm_kernel<1,128,0><<<grid,blk,0,stream>>>(A16,Wb,bias,res,C,Cb,M,N,K,ldc,g_norm); break;
      default: bgemm_kernel<0,128,0><<<grid,blk,0,stream>>>(A16,Wb,bias,res,C,Cb,M,N,K,ldc,g_norm); break;
    }
  } else {
    dim3 grid(N/64, (M+127)/128);
    switch(act){
      case 2: bgemm_kernel<2,64,0><<<grid,blk,0,stream>>>(A16,Wb,bias,res,C,Cb,M,N,K,ldc,g_norm); break;
      default: bgemm_kernel<0,64,0><<<grid,blk,0,stream>>>(A16,Wb,bias,res,C,Cb,M,N,K,ldc,g_norm); break;
    }
  }
}

extern "C" void kernel_launch(void* const* d_in, const int* in_sizes, int n_in,
                              void* d_out, int out_size, void* d_ws, size_t ws_size,
                              hipStream_t stream)
{
  (void)in_sizes; (void)n_in; (void)out_size; (void)ws_size;
  const float* x       = (const float*)d_in[0];
  const float* ts      = (const float*)d_in[1];
  const float* ode_w1  = (const float*)d_in[2];
  const float* ode_b1  = (const float*)d_in[3];
  const float* ode_w2  = (const float*)d_in[4];
  const float* ode_b2  = (const float*)d_in[5];
  const float* gru_wih = (const float*)d_in[6];
  const float* gru_whh = (const float*)d_in[7];
  const float* gru_bih = (const float*)d_in[8];
  const float* gru_bhh = (const float*)d_in[9];
  const float* te_a    = (const float*)d_in[10];
  const float* te_b    = (const float*)d_in[11];
  const float* t_in_w  = (const float*)d_in[12];
  const float* t_in_b  = (const float*)d_in[13];
  const float* t_out_w = (const float*)d_in[14];
  const float* t_out_b = (const float*)d_in[15];
  const float* t_ln1_w = (const float*)d_in[16];
  const float* t_ln1_b = (const float*)d_in[17];
  const float* t_ln2_w = (const float*)d_in[18];
  const float* t_ln2_b = (const float*)d_in[19];
  const float* t_ff1_w = (const float*)d_in[20];
  const float* t_ff1_b = (const float*)d_in[21];
  const float* t_ff2_w = (const float*)d_in[22];
  const float* t_ff2_b = (const float*)d_in[23];
  const float* t_lnf_w = (const float*)d_in[24];
  const float* t_lnf_b = (const float*)d_in[25];
  const float* ca_in_w = (const float*)d_in[26];
  const float* ca_in_b = (const float*)d_in[27];
  const float* ca_out_w= (const float*)d_in[28];
  const float* ca_out_b= (const float*)d_in[29];
  const float* ca_lin_w= (const float*)d_in[30];
  const float* ca_lin_b= (const float*)d_in[31];
  const float* ca_ln_w = (const float*)d_in[32];
  const float* ca_ln_b = (const float*)d_in[33];

  float* ws = (float*)d_ws;
  const size_t SZ = (size_t)ROWS * DM;
  // f32 pool
  float* deltab = ws + 0*SZ;
  float* accb   = ws + 1*SZ;
  float* fcur   = ws + 2*SZ;                 // ca pre-LN
  float* gx     = ws + 3*SZ;                 // 3*SZ
  float* zbuf   = ws + 6*SZ;
  float* hsb    = ws + 7*SZ;
  float* hbuf   = ws + 8*SZ;                                     // 2*BB*512 f32 (32KB)
  int*   flags  = (int*)(ws + 8*SZ + 8192);                      // BB*64 ints (2KB)
  float* dtrow  = ws + 8*SZ + 16384;                             // 8184 f32
  int*   srcrow = (int*)(ws + 8*SZ + 16384 + 8192);              // 8184 i32
  // bf16 pool
  unsigned short* u16 = (unsigned short*)(ws + 8*SZ + 16384 + 16384);
  unsigned short* delta16 = u16 + 0*SZ;
  unsigned short* y16     = u16 + 1*SZ;
  unsigned short* t16     = u16 + 2*SZ;
  unsigned short* hs16    = u16 + 3*SZ;
  unsigned short* ff1b16  = u16 + 4*SZ;      // 4*SZ; qkv16 aliases
  unsigned short* qkv16   = ff1b16;
  unsigned short* ao16    = delta16;
  unsigned short* hin16   = y16;
  unsigned short* cao16   = y16;
  unsigned short* ln16    = t16;
  // weights (one fused cast; offsets in elems = 4*float4-off)
  unsigned short* wb = u16 + 8*SZ;
  unsigned short* wb_ode1 = wb + 0;
  unsigned short* wb_ode2 = wb + 262144;
  unsigned short* wb_gwih = wb + 524288;
  unsigned short* wb_tin  = wb + 1310720;
  unsigned short* wb_tout = wb + 2883584;
  unsigned short* wb_ff1  = wb + 3407872;
  unsigned short* wb_ff2  = wb + 5505024;
  unsigned short* wb_cain = wb + 7602176;
  unsigned short* wb_caout= wb + 8388608;
  unsigned short* wb_calin= wb + 8650752;

  hipMemsetAsync(flags, 0, GRU_BLK*sizeof(int), stream);
  castall_kernel<<<(2228224+255)/256, 256, 0, stream>>>(
      ode_w1, ode_w2, gru_wih, t_in_w, t_out_w, t_ff1_w, t_ff2_w,
      ca_in_w, ca_out_w, ca_lin_w, wb);

  // ---- ODE (RK4), rk+states+zero fused into ode2 epilogues ----
  delta_kernel<<<ROWS1*DM/256, 256, 0, stream>>>(x, ts, deltab, delta16, dtrow, srcrow);
  RkArgs rk; rk.delta = deltab; rk.acc = accb; rk.y16 = y16;
  rk.dtrow = dtrow; rk.srcrow = srcrow; rk.x = x; rk.hin16 = hin16;
  const unsigned short* yin16 = delta16;
  const float was[4] = {1.f, 2.f, 2.f, 1.f};
  const float cys[4] = {0.5f, 0.5f, 1.f, 0.f};
  for (int s4 = 0; s4 < 4; s4++) {
    launch_bgemm(2, 64, yin16, wb_ode1, ode_b1, nullptr, nullptr, t16, ROWS1, 512, 512, 512, stream);
    rk.wa = was[s4]; rk.cy = cys[s4];
    dim3 grid(512/64, (ROWS1+127)/128), blk(256);
    if (s4 == 0)
      bgemm_kernel<0,64,1><<<grid,blk,0,stream>>>(t16, wb_ode2, ode_b2, nullptr, nullptr, nullptr, ROWS1, 512, 512, 512, rk);
    else if (s4 < 3)
      bgemm_kernel<0,64,2><<<grid,blk,0,stream>>>(t16, wb_ode2, ode_b2, nullptr, nullptr, nullptr, ROWS1, 512, 512, 512, rk);
    else
      bgemm_kernel<0,64,3><<<grid,blk,0,stream>>>(t16, wb_ode2, ode_b2, nullptr, nullptr, nullptr, ROWS1, 512, 512, 512, rk);
    yin16 = y16;
  }

  // ---- GRU ----
  launch_bgemm(0, 128, hin16, wb_gwih, gru_bih, nullptr, gx, nullptr, ROWS, 1536, 512, 1536, stream);
  gru_scan_kernel<<<GRU_BLK, 256, 0, stream>>>(gx, gru_whh, gru_bhh, hsb, hs16, hbuf, flags);

  // ---- transformer (2 layers, pre-norm, causal); timeenc fused into l0 ln1 ----
  for (int l = 0; l < 2; l++) {
    if (l == 0)
      ln_kernel<1,1><<<ROWS,256,0,stream>>>(x, t_ln1_w, t_ln1_b, ln16, ts, te_a, te_b, zbuf);
    else
      ln_kernel<1,0><<<ROWS,256,0,stream>>>(zbuf, t_ln1_w + 512, t_ln1_b + 512, ln16,
                                            nullptr, nullptr, nullptr, nullptr);
    launch_bgemm(0, 128, ln16, wb_tin + (size_t)l*1536*512, t_in_b + l*1536, nullptr, nullptr, qkv16, ROWS, 1536, 512, 1536, stream);
    mattn_kernel<1><<<dim3(64, TT/64), 256, 0, stream>>>(qkv16, ao16);
    launch_bgemm(0, 64, ao16, wb_tout + (size_t)l*512*512, t_out_b + l*512, zbuf, zbuf, nullptr, ROWS, 512, 512, 512, stream);
    ln_kernel<1,0><<<ROWS,256,0,stream>>>(zbuf, t_ln2_w + l*512, t_ln2_b + l*512, ln16,
                                          nullptr, nullptr, nullptr, nullptr);
    launch_bgemm(1, 128, ln16, wb_ff1 + (size_t)l*2048*512, t_ff1_b + l*2048, nullptr, nullptr, ff1b16, ROWS, 2048, 512, 2048, stream);
    launch_bgemm(0, 64, ff1b16, wb_ff2 + (size_t)l*512*2048, t_ff2_b + l*512, zbuf, zbuf, nullptr, ROWS, 512, 2048, 512, stream);
  }
  ln_kernel<1,0><<<ROWS,256,0,stream>>>(zbuf, t_lnf_w, t_lnf_b, ln16,
                                        nullptr, nullptr, nullptr, nullptr);

  // ---- cross attention ----
  launch_bgemm(0, 64,  hs16, wb_cain,           ca_in_b,       nullptr, nullptr, qkv16,       ROWS,  512, 512, 1536, stream);
  launch_bgemm(0, 128, ln16, wb_cain + 512*512, ca_in_b + 512, nullptr, nullptr, qkv16 + 512, ROWS, 1024, 512, 1536, stream);
  mattn_kernel<0><<<dim3(64, TT/64), 256, 0, stream>>>(qkv16, ao16);
  launch_bgemm(0, 64, ao16, wb_caout, ca_out_b, nullptr, nullptr, cao16, ROWS, 512, 512, 512, stream);
  launch_bgemm(0, 64, cao16, wb_calin, ca_lin_b, hsb, fcur, nullptr, ROWS, 512, 512, 512, stream);
  ln_kernel<0,0><<<ROWS,256,0,stream>>>(fcur, ca_ln_w, ca_ln_b, (float*)d_out,
                                        nullptr, nullptr, nullptr, nullptr);
}

// Round 10
// 2811.058 us; speedup vs baseline: 2.2684x; 2.2684x over previous
//
#include <hip/hip_runtime.h>
#include <math.h>

#define BB 8
#define TT 1024
#define DM 512
#define ROWS (BB*TT)     // 8192
#define ROWS1 (BB*(TT-1))// 8184
#define GRU_J 8
#define GRU_BLK (BB*64)  // 512 blocks

typedef __attribute__((ext_vector_type(4))) float f32x4;
typedef __attribute__((ext_vector_type(8))) short bf16x8;
typedef __attribute__((ext_vector_type(4))) short bf16x4;

#define GLOAD16(g, l) __builtin_amdgcn_global_load_lds( \
    (const __attribute__((address_space(1))) void*)(g), \
    (__attribute__((address_space(3))) void*)(l), 16, 0, 0)

struct RkArgs {
  const float* delta; float* acc; unsigned short* y16;
  const float* dtrow; const int* srcrow;
  const float* x; unsigned short* hin16;
  float wa, cy;
};

__device__ __forceinline__ float sigm_(float v){ return 1.f/(1.f+expf(-v)); }

__device__ __forceinline__ unsigned short f2bf(float f){
  unsigned u = __float_as_uint(f);
  return (unsigned short)((u + 0x7FFFu + ((u>>16)&1u)) >> 16);
}

// ---------------- fused weight cast (all 10 weights, 1 launch) ----------------
__global__ __launch_bounds__(256) void castall_kernel(
    const float* w0, const float* w1, const float* w2, const float* w3,
    const float* w4, const float* w5, const float* w6, const float* w7,
    const float* w8, const float* w9, unsigned short* __restrict__ o)
{
  int i = blockIdx.x*256 + threadIdx.x;           // in float4 units
  if (i >= 2228224) return;
  const float* src; int off;
  if      (i <   65536){ src=w0; off=0; }
  else if (i <  131072){ src=w1; off=65536; }
  else if (i <  327680){ src=w2; off=131072; }
  else if (i <  720896){ src=w3; off=327680; }
  else if (i <  851968){ src=w4; off=720896; }
  else if (i < 1376256){ src=w5; off=851968; }
  else if (i < 1900544){ src=w6; off=1376256; }
  else if (i < 2097152){ src=w7; off=1900544; }
  else if (i < 2162688){ src=w8; off=2097152; }
  else                 { src=w9; off=2162688; }
  float4 v = ((const float4*)src)[i - off];
  ushort4 u;
  u.x = f2bf(v.x); u.y = f2bf(v.y); u.z = f2bf(v.z); u.w = f2bf(v.w);
  ((ushort4*)o)[i] = u;
}

// ---------------- elementwise ----------------
__global__ __launch_bounds__(256) void delta_kernel(const float* __restrict__ x,
    const float* __restrict__ ts, float* __restrict__ delta,
    unsigned short* __restrict__ delta16,
    float* __restrict__ dtrow, int* __restrict__ srcrow)
{
  size_t i = (size_t)blockIdx.x*256 + threadIdx.x;
  int d = (int)(i & (DM-1));
  int r = (int)(i >> 9);
  int b = r / (TT-1), ii = r % (TT-1);
  float dt = ts[b*TT+ii+1] - ts[b*TT+ii];
  float x1 = x[((size_t)b*TT+ii+1)*DM + d];
  float x0 = x[((size_t)b*TT+ii)*DM + d];
  float v = (x1 - x0) / dt;
  delta[i] = v;
  delta16[i] = f2bf(v);
  if (d == 0) { dtrow[r] = dt; srcrow[r] = b*TT + ii; }
}

// ---------------- LayerNorm (block per row, D=512) ----------------
// TE=1: input = x + time-encoding (fused timeenc, layer-0 ln1); also writes zout f32.
template<int BF, int TE>
__global__ __launch_bounds__(256) void ln_kernel(const float* __restrict__ x,
    const float* __restrict__ w, const float* __restrict__ b,
    void* __restrict__ outp,
    const float* ts, const float* te_a, const float* te_b, float* zout)
{
  int row = blockIdx.x;
  int tid = threadIdx.x;
  const float* xr = x + (size_t)row*DM;
  float2 v = *(const float2*)(xr + tid*2);
  if (TE) {
    float t = ts[row];
    int d0 = tid*2;
    int fi = d0 >> 2;
    float fr = expf(-(float)fi * 0.061606661f) * 1.5707964f;
    float ph = t * fr;
    float tm0 = ((d0 & 3) == 0) ? sinf(ph) : cosf(ph);
    float tm1 = t*te_a[tid] + te_b[tid];
    v.x += tm0; v.y += tm1;
    *(float2*)(zout + (size_t)row*DM + tid*2) = v;
  }
  float s = v.x+v.y, sq = v.x*v.x + v.y*v.y;
  #pragma unroll
  for (int off=1; off<64; off<<=1){ s += __shfl_xor(s,off); sq += __shfl_xor(sq,off); }
  __shared__ float rs[4], rq[4];
  int wid = tid>>6;
  if ((tid&63)==0){ rs[wid]=s; rq[wid]=sq; }
  __syncthreads();
  s = rs[0]+rs[1]+rs[2]+rs[3];
  sq = rq[0]+rq[1]+rq[2]+rq[3];
  float mean = s*(1.f/DM);
  float var = sq*(1.f/DM) - mean*mean;
  float inv = rsqrtf(var + 1e-5f);
  float2 wv = *(const float2*)(w + tid*2);
  float2 bv = *(const float2*)(b + tid*2);
  float ox = (v.x-mean)*inv*wv.x + bv.x;
  float oy = (v.y-mean)*inv*wv.y + bv.y;
  if (BF) {
    ushort2 u; u.x = f2bf(ox); u.y = f2bf(oy);
    *(ushort2*)((unsigned short*)outp + (size_t)row*DM + tid*2) = u;
  } else {
    float2 o; o.x = ox; o.y = oy;
    *(float2*)((float*)outp + (size_t)row*DM + tid*2) = o;
  }
}

// ---------------- bf16 MFMA GEMM, global_load_lds staging ----------------
// Linear LDS [rows][32] bf16 (64B rows). Width-16 global_load_lds staging keeps
// loads in flight until the pre-barrier drain (m97 structure).
// RKM: 0 none, 1 RK-init, 2 RK-mid, 3 RK-final(states+zero) epilogues (ldc==512).
template<int ACT, int TN, int RKM>
__global__ __launch_bounds__(256) void bgemm_kernel(
    const unsigned short* __restrict__ A16, const unsigned short* __restrict__ Wb,
    const float* __restrict__ bias, const float* res,
    float* C, unsigned short* Cb, int M, int N, int K, int ldc, RkArgs rk)
{
  const int NJ = TN/32;
  __shared__ __align__(16) unsigned short Al[2][128*32];
  __shared__ __align__(16) unsigned short Wl[2][TN*32];
  const int bm = blockIdx.y*128, bn = blockIdx.x*TN;
  const int tid = threadIdx.x;
  const int lane = tid & 63, wv = tid >> 6;
  const int wm = (wv&1)*64, wn = (wv>>1)*(TN/2);
  const int fl = lane & 15, fk = (lane>>4)*8;
  const int srw = lane >> 2;         // row within 16-row group
  const int scl = (lane & 3)*8;      // 16B slot (elems)
  f32x4 acc[4][NJ];
  #pragma unroll
  for (int i=0;i<4;i++)
    #pragma unroll
    for (int j=0;j<NJ;j++) acc[i][j] = (f32x4){0.f,0.f,0.f,0.f};

  const int nk = K >> 5;

  auto stage = [&](int buf, int kt){
    int k0 = kt*32;
    #pragma unroll
    for (int j=0;j<2;j++){
      int r = wv*32 + j*16 + srw;
      GLOAD16(A16 + (size_t)(bm + r)*K + k0 + scl,
              &Al[buf][(wv*32 + j*16)*32]);
    }
    if (TN == 128) {
      #pragma unroll
      for (int j=0;j<2;j++){
        int r = wv*32 + j*16 + srw;
        GLOAD16(Wb + (size_t)(bn + r)*K + k0 + scl,
                &Wl[buf][(wv*32 + j*16)*32]);
      }
    } else {
      int r = wv*16 + srw;
      GLOAD16(Wb + (size_t)(bn + r)*K + k0 + scl,
              &Wl[buf][(wv*16)*32]);
    }
  };

  stage(0, 0);
  int buf = 0;
  for (int kt = 0; kt < nk; ++kt) {
    __syncthreads();                 // drains vmcnt -> buf ready
    if (kt+1 < nk) stage(buf^1, kt+1);
    bf16x8 av[4], wvv[NJ];
    #pragma unroll
    for (int i=0;i<4;i++) av[i] = *(const bf16x8*)&Al[buf][(wm + i*16 + fl)*32 + fk];
    #pragma unroll
    for (int j=0;j<NJ;j++) wvv[j] = *(const bf16x8*)&Wl[buf][(wn + j*16 + fl)*32 + fk];
    #pragma unroll
    for (int i=0;i<4;i++)
      #pragma unroll
      for (int j=0;j<NJ;j++)
        acc[i][j] = __builtin_amdgcn_mfma_f32_16x16x32_bf16(av[i], wvv[j], acc[i][j], 0, 0, 0);
    buf ^= 1;
  }

  // epilogue: C/D layout col=lane&15, row=(lane>>4)*4+reg
  #pragma unroll
  for (int j=0;j<NJ;j++){
    int gn = bn + wn + j*16 + fl;
    float bv = bias[gn];
    #pragma unroll
    for (int i=0;i<4;i++){
      #pragma unroll
      for (int r=0;r<4;r++){
        int gm = bm + wm + i*16 + (lane>>4)*4 + r;
        if (gm >= M) continue;
        float v = acc[i][j][r] + bv;
        if (ACT==1) v = fmaxf(v, 0.f);
        if (ACT==2) v = tanhf(v);
        if (RKM == 0) {
          if (res) v += res[(size_t)gm*ldc + gn];
          if (C)  C[(size_t)gm*ldc + gn] = v;
          if (Cb) Cb[(size_t)gm*ldc + gn] = f2bf(v);
        } else {
          size_t idx = (size_t)gm*512 + gn;
          float dt = rk.dtrow[gm];
          if (RKM == 1) {
            rk.acc[idx] = v;
            rk.y16[idx] = f2bf(rk.delta[idx] + rk.cy*dt*v);
          } else if (RKM == 2) {
            rk.acc[idx] += rk.wa*v;
            rk.y16[idx] = f2bf(rk.delta[idx] + rk.cy*dt*v);
          } else {
            float a = rk.acc[idx] + v;
            int srow = rk.srcrow[gm];
            rk.hin16[((size_t)srow+1)*512 + gn] =
                f2bf(rk.x[(size_t)srow*512 + gn] + dt*(1.f/6.f)*a);
            if ((srow & (TT-1)) == 0)            // fused zero of t=0 row (after-RK safe)
              rk.hin16[(size_t)srow*512 + gn] = 0;
          }
        }
      }
    }
  }
}

// ---------------- MFMA flash attention ----------------
template<int CAUSAL>
__global__ __launch_bounds__(256) void mattn_kernel(
    const unsigned short* __restrict__ QKV, unsigned short* __restrict__ O)
{
  __shared__ __align__(16) unsigned short Kl[32][72];
  __shared__ __align__(16) unsigned short Vt[64][36];
  __shared__ __align__(16) unsigned short Pl[4][16][40];
  const int b = blockIdx.x >> 3, h = blockIdx.x & 7;
  const int q0 = blockIdx.y * 64;
  const int tid = threadIdx.x;
  const int lane = tid & 63, wid = tid >> 6;
  const int lq = lane & 15, g = lane >> 4;
  const size_t rowbase = (size_t)b*TT;

  bf16x8 qf0, qf1;
  {
    const unsigned short* qp = QKV + (rowbase + q0 + wid*16 + lq)*1536 + h*64 + g*8;
    qf0 = *(const bf16x8*)qp;
    qf1 = *(const bf16x8*)(qp + 32);
  }
  f32x4 o[4];
  #pragma unroll
  for (int dt=0; dt<4; dt++) o[dt] = (f32x4){0.f,0.f,0.f,0.f};
  float mr[4] = {-1e30f,-1e30f,-1e30f,-1e30f};
  float Lr[4] = {0.f,0.f,0.f,0.f};

  const int nkt = CAUSAL ? (q0/32 + 2) : (TT/32);
  const int qwmax = q0 + wid*16 + 15;
  const int sr = tid >> 3, scol = (tid & 7) * 8;

  for (int kt = 0; kt < nkt; ++kt) {
    const int k0 = kt*32;
    __syncthreads();
    *(uint4*)&Kl[sr][scol] = *(const uint4*)(QKV + (rowbase + k0 + sr)*1536 + 512 + h*64 + scol);
    {
      uint4 vv = *(const uint4*)(QKV + (rowbase + k0 + sr)*1536 + 1024 + h*64 + scol);
      const unsigned short* vs = (const unsigned short*)&vv;
      #pragma unroll
      for (int i=0;i<8;i++) Vt[scol+i][sr] = vs[i];
    }
    __syncthreads();
    if (CAUSAL && k0 > qwmax) continue;

    f32x4 st0 = (f32x4){0.f,0.f,0.f,0.f}, st1 = (f32x4){0.f,0.f,0.f,0.f};
    {
      bf16x8 kb;
      kb = *(const bf16x8*)&Kl[lq][g*8];
      st0 = __builtin_amdgcn_mfma_f32_16x16x32_bf16(qf0, kb, st0, 0,0,0);
      kb = *(const bf16x8*)&Kl[lq][g*8+32];
      st0 = __builtin_amdgcn_mfma_f32_16x16x32_bf16(qf1, kb, st0, 0,0,0);
      kb = *(const bf16x8*)&Kl[16+lq][g*8];
      st1 = __builtin_amdgcn_mfma_f32_16x16x32_bf16(qf0, kb, st1, 0,0,0);
      kb = *(const bf16x8*)&Kl[16+lq][g*8+32];
      st1 = __builtin_amdgcn_mfma_f32_16x16x32_bf16(qf1, kb, st1, 0,0,0);
    }
    float s0[4], s1[4];
    #pragma unroll
    for (int r=0;r<4;r++){ s0[r] = st0[r]*0.125f; s1[r] = st1[r]*0.125f; }
    if (CAUSAL) {
      int kg0 = k0 + lq, kg1 = k0 + 16 + lq;
      #pragma unroll
      for (int r=0;r<4;r++){
        int qg = q0 + wid*16 + 4*g + r;
        if (kg0 > qg) s0[r] = -1e30f;
        if (kg1 > qg) s1[r] = -1e30f;
      }
    }
    #pragma unroll
    for (int r=0;r<4;r++){
      float v = fmaxf(s0[r], s1[r]);
      v = fmaxf(v, __shfl_xor(v,1));
      v = fmaxf(v, __shfl_xor(v,2));
      v = fmaxf(v, __shfl_xor(v,4));
      v = fmaxf(v, __shfl_xor(v,8));
      float mn = fmaxf(mr[r], v);
      float scl = expf(mr[r] - mn);
      mr[r] = mn;
      float p0 = expf(s0[r] - mn);
      float p1 = expf(s1[r] - mn);
      float lt = p0 + p1;
      lt += __shfl_xor(lt,1); lt += __shfl_xor(lt,2);
      lt += __shfl_xor(lt,4); lt += __shfl_xor(lt,8);
      Lr[r] = Lr[r]*scl + lt;
      o[0][r] *= scl; o[1][r] *= scl; o[2][r] *= scl; o[3][r] *= scl;
      Pl[wid][4*g+r][lq]    = f2bf(p0);
      Pl[wid][4*g+r][16+lq] = f2bf(p1);
    }
    bf16x8 ap = *(const bf16x8*)&Pl[wid][lq][g*8];
    #pragma unroll
    for (int dt=0; dt<4; dt++){
      bf16x4 a4 = *(const bf16x4*)&Vt[lq+16*dt][g*8];
      bf16x4 b4 = *(const bf16x4*)&Vt[lq+16*dt][g*8+4];
      bf16x8 vb = __builtin_shufflevector(a4, b4, 0,1,2,3,4,5,6,7);
      o[dt] = __builtin_amdgcn_mfma_f32_16x16x32_bf16(ap, vb, o[dt], 0,0,0);
    }
  }

  #pragma unroll
  for (int r=0;r<4;r++){
    float inv = 1.f / Lr[r];
    int qg = q0 + wid*16 + 4*g + r;
    unsigned short* op = O + (rowbase + qg)*DM + h*64 + lq;
    op[0]  = f2bf(o[0][r]*inv);
    op[16] = f2bf(o[1][r]*inv);
    op[32] = f2bf(o[2][r]*inv);
    op[48] = f2bf(o[3][r]*inv);
  }
}

// ---------------- GRU scan v4.1 (RESTORED from R8): tagged-value sync ----------------
// The poll IS the data load: (f32,tag) packed in 64-bit relaxed agent atomics.
// One MALL RTT to publish+consume. v5's flag indirection (3 serialized RTTs)
// regressed 3x — do not reintroduce.
__global__ __launch_bounds__(256) void gru_scan_kernel(
    const float* __restrict__ gx,
    const float* __restrict__ whh,
    const float* __restrict__ bhh,
    float* __restrict__ Hs,
    unsigned short* __restrict__ Hsb,
    unsigned long long* hbuf)
{
  __shared__ float wlds[3][GRU_J][512];
  __shared__ float hsp[512];
  const int blk = blockIdx.x;
  const int b = blk & 7;
  const int g = blk >> 3;
  const int j0 = g * GRU_J;
  const int tid = threadIdx.x;

  for (int idx = tid; idx < 3*GRU_J*512/4; idx += 256) {
    int f = idx*4;
    int gate = f >> 12;
    int rem = f & 4095;
    int jj = rem >> 9, k = rem & 511;
    *(float4*)&wlds[gate][jj][k] = *(const float4*)&whh[(size_t)(gate*512 + j0 + jj)*512 + k];
  }
  const int row = tid >> 5;
  const int kl = tid & 31;
  const bool fin = (kl == 0);
  float bh0=0.f, bh1=0.f, bh2=0.f;
  if (fin) { bh0 = bhh[j0+row]; bh1 = bhh[512+j0+row]; bh2 = bhh[1024+j0+row]; }
  __syncthreads();

  for (int t = 0; t < TT; t++) {
    float g0=0.f, g1=0.f, g2=0.f;
    if (fin) {
      const float* gxr = gx + ((size_t)b*TT + t)*1536 + j0 + row;
      g0 = gxr[0]; g1 = gxr[512]; g2 = gxr[1024];
    }
    if (t == 0) {
      hsp[tid] = 0.f; hsp[tid+256] = 0.f;
    } else {
      const unsigned want = (unsigned)t;
      unsigned long long* src = hbuf + ((size_t)((t-1)&1)*BB + b)*512;
      unsigned long long u0, u1;
      for (;;) {
        u0 = __hip_atomic_load(src + tid,       __ATOMIC_RELAXED, __HIP_MEMORY_SCOPE_AGENT);
        u1 = __hip_atomic_load(src + tid + 256, __ATOMIC_RELAXED, __HIP_MEMORY_SCOPE_AGENT);
        if (((unsigned)(u0>>32) == want) & ((unsigned)(u1>>32) == want)) break;
        __builtin_amdgcn_s_sleep(1);
      }
      hsp[tid]     = __uint_as_float((unsigned)u0);
      hsp[tid+256] = __uint_as_float((unsigned)u1);
    }
    __syncthreads();

    float s0=0.f, s1=0.f, s2=0.f;
    #pragma unroll
    for (int j=0;j<4;j++){
      int k = kl*4 + j*128;
      float4 h4 = *(const float4*)&hsp[k];
      float4 a = *(const float4*)&wlds[0][row][k];
      float4 c = *(const float4*)&wlds[1][row][k];
      float4 d = *(const float4*)&wlds[2][row][k];
      s0 += a.x*h4.x + a.y*h4.y + a.z*h4.z + a.w*h4.w;
      s1 += c.x*h4.x + c.y*h4.y + c.z*h4.z + c.w*h4.w;
      s2 += d.x*h4.x + d.y*h4.y + d.z*h4.z + d.w*h4.w;
    }
    #pragma unroll
    for (int off=1; off<32; off<<=1) {
      s0 += __shfl_xor(s0, off);
      s1 += __shfl_xor(s1, off);
      s2 += __shfl_xor(s2, off);
    }
    if (fin) {
      float r  = sigm_(g0 + s0 + bh0);
      float z  = sigm_(g1 + s1 + bh1);
      float n  = tanhf(g2 + r*(s2 + bh2));
      float hold = hsp[j0 + row];
      float hnew = (1.f - z)*n + z*hold;
      size_t off = ((size_t)b*TT + t)*DM + j0 + row;
      Hs[off]  = hnew;
      Hsb[off] = f2bf(hnew);
      unsigned long long pk = ((unsigned long long)(unsigned)(t+1) << 32) | __float_as_uint(hnew);
      __hip_atomic_store(&hbuf[((size_t)(t&1)*BB + b)*512 + j0 + row], pk,
                         __ATOMIC_RELAXED, __HIP_MEMORY_SCOPE_AGENT);
    }
    __syncthreads();
  }
}

// ---------------- host ----------------
static RkArgs g_norm = {};

static void launch_bgemm(int act, int tn, const unsigned short* A16, const unsigned short* Wb,
                         const float* bias, const float* res, float* C, unsigned short* Cb,
                         int M, int N, int K, int ldc, hipStream_t stream)
{
  dim3 blk(256);
  if (tn == 128) {
    dim3 grid(N/128, (M+127)/128);
    switch(act){
      case 1: bgemm_kernel<1,128,0><<<grid,blk,0,stream>>>(A16,Wb,bias,res,C,Cb,M,N,K,ldc,g_norm); break;
      default: bgemm_kernel<0,128,0><<<grid,blk,0,stream>>>(A16,Wb,bias,res,C,Cb,M,N,K,ldc,g_norm); break;
    }
  } else {
    dim3 grid(N/64, (M+127)/128);
    switch(act){
      case 2: bgemm_kernel<2,64,0><<<grid,blk,0,stream>>>(A16,Wb,bias,res,C,Cb,M,N,K,ldc,g_norm); break;
      default: bgemm_kernel<0,64,0><<<grid,blk,0,stream>>>(A16,Wb,bias,res,C,Cb,M,N,K,ldc,g_norm); break;
    }
  }
}

extern "C" void kernel_launch(void* const* d_in, const int* in_sizes, int n_in,
                              void* d_out, int out_size, void* d_ws, size_t ws_size,
                              hipStream_t stream)
{
  (void)in_sizes; (void)n_in; (void)out_size; (void)ws_size;
  const float* x       = (const float*)d_in[0];
  const float* ts      = (const float*)d_in[1];
  const float* ode_w1  = (const float*)d_in[2];
  const float* ode_b1  = (const float*)d_in[3];
  const float* ode_w2  = (const float*)d_in[4];
  const float* ode_b2  = (const float*)d_in[5];
  const float* gru_wih = (const float*)d_in[6];
  const float* gru_whh = (const float*)d_in[7];
  const float* gru_bih = (const float*)d_in[8];
  const float* gru_bhh = (const float*)d_in[9];
  const float* te_a    = (const float*)d_in[10];
  const float* te_b    = (const float*)d_in[11];
  const float* t_in_w  = (const float*)d_in[12];
  const float* t_in_b  = (const float*)d_in[13];
  const float* t_out_w = (const float*)d_in[14];
  const float* t_out_b = (const float*)d_in[15];
  const float* t_ln1_w = (const float*)d_in[16];
  const float* t_ln1_b = (const float*)d_in[17];
  const float* t_ln2_w = (const float*)d_in[18];
  const float* t_ln2_b = (const float*)d_in[19];
  const float* t_ff1_w = (const float*)d_in[20];
  const float* t_ff1_b = (const float*)d_in[21];
  const float* t_ff2_w = (const float*)d_in[22];
  const float* t_ff2_b = (const float*)d_in[23];
  const float* t_lnf_w = (const float*)d_in[24];
  const float* t_lnf_b = (const float*)d_in[25];
  const float* ca_in_w = (const float*)d_in[26];
  const float* ca_in_b = (const float*)d_in[27];
  const float* ca_out_w= (const float*)d_in[28];
  const float* ca_out_b= (const float*)d_in[29];
  const float* ca_lin_w= (const float*)d_in[30];
  const float* ca_lin_b= (const float*)d_in[31];
  const float* ca_ln_w = (const float*)d_in[32];
  const float* ca_ln_b = (const float*)d_in[33];

  float* ws = (float*)d_ws;
  const size_t SZ = (size_t)ROWS * DM;
  // f32 pool
  float* deltab = ws + 0*SZ;
  float* accb   = ws + 1*SZ;
  float* fcur   = ws + 2*SZ;                 // ca pre-LN
  float* gx     = ws + 3*SZ;                 // 3*SZ
  float* zbuf   = ws + 6*SZ;
  float* hsb    = ws + 7*SZ;
  unsigned long long* hbuf = (unsigned long long*)(ws + 8*SZ);   // 64KB tagged
  float* dtrow  = ws + 8*SZ + 16384;                             // 8184 f32
  int*   srcrow = (int*)(ws + 8*SZ + 16384 + 8192);              // 8184 i32
  // bf16 pool
  unsigned short* u16 = (unsigned short*)(ws + 8*SZ + 16384 + 16384);
  unsigned short* delta16 = u16 + 0*SZ;
  unsigned short* y16     = u16 + 1*SZ;
  unsigned short* t16     = u16 + 2*SZ;
  unsigned short* hs16    = u16 + 3*SZ;
  unsigned short* ff1b16  = u16 + 4*SZ;      // 4*SZ; qkv16 aliases
  unsigned short* qkv16   = ff1b16;
  unsigned short* ao16    = delta16;
  unsigned short* hin16   = y16;
  unsigned short* cao16   = y16;
  unsigned short* ln16    = t16;
  // weights (one fused cast; offsets in elems = 4*float4-off)
  unsigned short* wb = u16 + 8*SZ;
  unsigned short* wb_ode1 = wb + 0;
  unsigned short* wb_ode2 = wb + 262144;
  unsigned short* wb_gwih = wb + 524288;
  unsigned short* wb_tin  = wb + 1310720;
  unsigned short* wb_tout = wb + 2883584;
  unsigned short* wb_ff1  = wb + 3407872;
  unsigned short* wb_ff2  = wb + 5505024;
  unsigned short* wb_cain = wb + 7602176;
  unsigned short* wb_caout= wb + 8388608;
  unsigned short* wb_calin= wb + 8650752;

  castall_kernel<<<(2228224+255)/256, 256, 0, stream>>>(
      ode_w1, ode_w2, gru_wih, t_in_w, t_out_w, t_ff1_w, t_ff2_w,
      ca_in_w, ca_out_w, ca_lin_w, wb);

  // ---- ODE (RK4), rk+states+zero fused into ode2 epilogues ----
  delta_kernel<<<ROWS1*DM/256, 256, 0, stream>>>(x, ts, deltab, delta16, dtrow, srcrow);
  RkArgs rk; rk.delta = deltab; rk.acc = accb; rk.y16 = y16;
  rk.dtrow = dtrow; rk.srcrow = srcrow; rk.x = x; rk.hin16 = hin16;
  const unsigned short* yin16 = delta16;
  const float was[4] = {1.f, 2.f, 2.f, 1.f};
  const float cys[4] = {0.5f, 0.5f, 1.f, 0.f};
  for (int s4 = 0; s4 < 4; s4++) {
    launch_bgemm(2, 64, yin16, wb_ode1, ode_b1, nullptr, nullptr, t16, ROWS1, 512, 512, 512, stream);
    rk.wa = was[s4]; rk.cy = cys[s4];
    dim3 grid(512/64, (ROWS1+127)/128), blk(256);
    if (s4 == 0)
      bgemm_kernel<0,64,1><<<grid,blk,0,stream>>>(t16, wb_ode2, ode_b2, nullptr, nullptr, nullptr, ROWS1, 512, 512, 512, rk);
    else if (s4 < 3)
      bgemm_kernel<0,64,2><<<grid,blk,0,stream>>>(t16, wb_ode2, ode_b2, nullptr, nullptr, nullptr, ROWS1, 512, 512, 512, rk);
    else
      bgemm_kernel<0,64,3><<<grid,blk,0,stream>>>(t16, wb_ode2, ode_b2, nullptr, nullptr, nullptr, ROWS1, 512, 512, 512, rk);
    yin16 = y16;
  }

  // ---- GRU ----
  launch_bgemm(0, 128, hin16, wb_gwih, gru_bih, nullptr, gx, nullptr, ROWS, 1536, 512, 1536, stream);
  gru_scan_kernel<<<GRU_BLK, 256, 0, stream>>>(gx, gru_whh, gru_bhh, hsb, hs16, hbuf);

  // ---- transformer (2 layers, pre-norm, causal); timeenc fused into l0 ln1 ----
  for (int l = 0; l < 2; l++) {
    if (l == 0)
      ln_kernel<1,1><<<ROWS,256,0,stream>>>(x, t_ln1_w, t_ln1_b, ln16, ts, te_a, te_b, zbuf);
    else
      ln_kernel<1,0><<<ROWS,256,0,stream>>>(zbuf, t_ln1_w + 512, t_ln1_b + 512, ln16,
                                            nullptr, nullptr, nullptr, nullptr);
    launch_bgemm(0, 128, ln16, wb_tin + (size_t)l*1536*512, t_in_b + l*1536, nullptr, nullptr, qkv16, ROWS, 1536, 512, 1536, stream);
    mattn_kernel<1><<<dim3(64, TT/64), 256, 0, stream>>>(qkv16, ao16);
    launch_bgemm(0, 64, ao16, wb_tout + (size_t)l*512*512, t_out_b + l*512, zbuf, zbuf, nullptr, ROWS, 512, 512, 512, stream);
    ln_kernel<1,0><<<ROWS,256,0,stream>>>(zbuf, t_ln2_w + l*512, t_ln2_b + l*512, ln16,
                                          nullptr, nullptr, nullptr, nullptr);
    launch_bgemm(1, 128, ln16, wb_ff1 + (size_t)l*2048*512, t_ff1_b + l*2048, nullptr, nullptr, ff1b16, ROWS, 2048, 512, 2048, stream);
    launch_bgemm(0, 64, ff1b16, wb_ff2 + (size_t)l*512*2048, t_ff2_b + l*512, zbuf, zbuf, nullptr, ROWS, 512, 2048, 512, stream);
  }
  ln_kernel<1,0><<<ROWS,256,0,stream>>>(zbuf, t_lnf_w, t_lnf_b, ln16,
                                        nullptr, nullptr, nullptr, nullptr);

  // ---- cross attention ----
  launch_bgemm(0, 64,  hs16, wb_cain,           ca_in_b,       nullptr, nullptr, qkv16,       ROWS,  512, 512, 1536, stream);
  launch_bgemm(0, 128, ln16, wb_cain + 512*512, ca_in_b + 512, nullptr, nullptr, qkv16 + 512, ROWS, 1024, 512, 1536, stream);
  mattn_kernel<0><<<dim3(64, TT/64), 256, 0, stream>>>(qkv16, ao16);
  launch_bgemm(0, 64, ao16, wb_caout, ca_out_b, nullptr, nullptr, cao16, ROWS, 512, 512, 512, stream);
  launch_bgemm(0, 64, cao16, wb_calin, ca_lin_b, hsb, fcur, nullptr, ROWS, 512, 512, 512, stream);
  ln_kernel<0,0><<<ROWS,256,0,stream>>>(fcur, ca_ln_w, ca_ln_b, (float*)d_out,
                                        nullptr, nullptr, nullptr, nullptr);
}

// Round 11
// 2798.286 us; speedup vs baseline: 2.2788x; 1.0046x over previous
//
#include <hip/hip_runtime.h>
#include <math.h>

#define BB 8
#define TT 1024
#define DM 512
#define ROWS (BB*TT)     // 8192
#define ROWS1 (BB*(TT-1))// 8184
#define GRU_J 16         // hidden dims per block
#define GRU_GPB 32       // blocks per batch
#define GRU_BLK (BB*GRU_GPB)  // 256 blocks = 1/CU

typedef __attribute__((ext_vector_type(4))) float f32x4;
typedef __attribute__((ext_vector_type(8))) short bf16x8;
typedef __attribute__((ext_vector_type(4))) short bf16x4;

#define GLOAD16(g, l) __builtin_amdgcn_global_load_lds( \
    (const __attribute__((address_space(1))) void*)(g), \
    (__attribute__((address_space(3))) void*)(l), 16, 0, 0)

struct RkArgs {
  const float* delta; float* acc; unsigned short* y16;
  const float* dtrow; const int* srcrow;
  const float* x; unsigned short* hin16;
  float wa, cy;
};

__device__ __forceinline__ float sigm_(float v){ return 1.f/(1.f+expf(-v)); }

__device__ __forceinline__ unsigned short f2bf(float f){
  unsigned u = __float_as_uint(f);
  return (unsigned short)((u + 0x7FFFu + ((u>>16)&1u)) >> 16);
}

// ---------------- fused weight cast (all 10 weights, 1 launch) ----------------
__global__ __launch_bounds__(256) void castall_kernel(
    const float* w0, const float* w1, const float* w2, const float* w3,
    const float* w4, const float* w5, const float* w6, const float* w7,
    const float* w8, const float* w9, unsigned short* __restrict__ o)
{
  int i = blockIdx.x*256 + threadIdx.x;           // in float4 units
  if (i >= 2228224) return;
  const float* src; int off;
  if      (i <   65536){ src=w0; off=0; }
  else if (i <  131072){ src=w1; off=65536; }
  else if (i <  327680){ src=w2; off=131072; }
  else if (i <  720896){ src=w3; off=327680; }
  else if (i <  851968){ src=w4; off=720896; }
  else if (i < 1376256){ src=w5; off=851968; }
  else if (i < 1900544){ src=w6; off=1376256; }
  else if (i < 2097152){ src=w7; off=1900544; }
  else if (i < 2162688){ src=w8; off=2097152; }
  else                 { src=w9; off=2162688; }
  float4 v = ((const float4*)src)[i - off];
  ushort4 u;
  u.x = f2bf(v.x); u.y = f2bf(v.y); u.z = f2bf(v.z); u.w = f2bf(v.w);
  ((ushort4*)o)[i] = u;
}

// ---------------- elementwise ----------------
__global__ __launch_bounds__(256) void delta_kernel(const float* __restrict__ x,
    const float* __restrict__ ts, float* __restrict__ delta,
    unsigned short* __restrict__ delta16,
    float* __restrict__ dtrow, int* __restrict__ srcrow)
{
  size_t i = (size_t)blockIdx.x*256 + threadIdx.x;
  int d = (int)(i & (DM-1));
  int r = (int)(i >> 9);
  int b = r / (TT-1), ii = r % (TT-1);
  float dt = ts[b*TT+ii+1] - ts[b*TT+ii];
  float x1 = x[((size_t)b*TT+ii+1)*DM + d];
  float x0 = x[((size_t)b*TT+ii)*DM + d];
  float v = (x1 - x0) / dt;
  delta[i] = v;
  delta16[i] = f2bf(v);
  if (d == 0) { dtrow[r] = dt; srcrow[r] = b*TT + ii; }
}

// ---------------- LayerNorm (block per row, D=512) ----------------
// TE=1: input = x + time-encoding (fused timeenc, layer-0 ln1); also writes zout f32.
template<int BF, int TE>
__global__ __launch_bounds__(256) void ln_kernel(const float* __restrict__ x,
    const float* __restrict__ w, const float* __restrict__ b,
    void* __restrict__ outp,
    const float* ts, const float* te_a, const float* te_b, float* zout)
{
  int row = blockIdx.x;
  int tid = threadIdx.x;
  const float* xr = x + (size_t)row*DM;
  float2 v = *(const float2*)(xr + tid*2);
  if (TE) {
    float t = ts[row];
    int d0 = tid*2;
    int fi = d0 >> 2;
    float fr = expf(-(float)fi * 0.061606661f) * 1.5707964f;
    float ph = t * fr;
    float tm0 = ((d0 & 3) == 0) ? sinf(ph) : cosf(ph);
    float tm1 = t*te_a[tid] + te_b[tid];
    v.x += tm0; v.y += tm1;
    *(float2*)(zout + (size_t)row*DM + tid*2) = v;
  }
  float s = v.x+v.y, sq = v.x*v.x + v.y*v.y;
  #pragma unroll
  for (int off=1; off<64; off<<=1){ s += __shfl_xor(s,off); sq += __shfl_xor(sq,off); }
  __shared__ float rs[4], rq[4];
  int wid = tid>>6;
  if ((tid&63)==0){ rs[wid]=s; rq[wid]=sq; }
  __syncthreads();
  s = rs[0]+rs[1]+rs[2]+rs[3];
  sq = rq[0]+rq[1]+rq[2]+rq[3];
  float mean = s*(1.f/DM);
  float var = sq*(1.f/DM) - mean*mean;
  float inv = rsqrtf(var + 1e-5f);
  float2 wv = *(const float2*)(w + tid*2);
  float2 bv = *(const float2*)(b + tid*2);
  float ox = (v.x-mean)*inv*wv.x + bv.x;
  float oy = (v.y-mean)*inv*wv.y + bv.y;
  if (BF) {
    ushort2 u; u.x = f2bf(ox); u.y = f2bf(oy);
    *(ushort2*)((unsigned short*)outp + (size_t)row*DM + tid*2) = u;
  } else {
    float2 o; o.x = ox; o.y = oy;
    *(float2*)((float*)outp + (size_t)row*DM + tid*2) = o;
  }
}

// ---------------- bf16 MFMA GEMM, global_load_lds staging ----------------
template<int ACT, int TN, int RKM>
__global__ __launch_bounds__(256) void bgemm_kernel(
    const unsigned short* __restrict__ A16, const unsigned short* __restrict__ Wb,
    const float* __restrict__ bias, const float* res,
    float* C, unsigned short* Cb, int M, int N, int K, int ldc, RkArgs rk)
{
  const int NJ = TN/32;
  __shared__ __align__(16) unsigned short Al[2][128*32];
  __shared__ __align__(16) unsigned short Wl[2][TN*32];
  const int bm = blockIdx.y*128, bn = blockIdx.x*TN;
  const int tid = threadIdx.x;
  const int lane = tid & 63, wv = tid >> 6;
  const int wm = (wv&1)*64, wn = (wv>>1)*(TN/2);
  const int fl = lane & 15, fk = (lane>>4)*8;
  const int srw = lane >> 2;         // row within 16-row group
  const int scl = (lane & 3)*8;      // 16B slot (elems)
  f32x4 acc[4][NJ];
  #pragma unroll
  for (int i=0;i<4;i++)
    #pragma unroll
    for (int j=0;j<NJ;j++) acc[i][j] = (f32x4){0.f,0.f,0.f,0.f};

  const int nk = K >> 5;

  auto stage = [&](int buf, int kt){
    int k0 = kt*32;
    #pragma unroll
    for (int j=0;j<2;j++){
      int r = wv*32 + j*16 + srw;
      GLOAD16(A16 + (size_t)(bm + r)*K + k0 + scl,
              &Al[buf][(wv*32 + j*16)*32]);
    }
    if (TN == 128) {
      #pragma unroll
      for (int j=0;j<2;j++){
        int r = wv*32 + j*16 + srw;
        GLOAD16(Wb + (size_t)(bn + r)*K + k0 + scl,
                &Wl[buf][(wv*32 + j*16)*32]);
      }
    } else {
      int r = wv*16 + srw;
      GLOAD16(Wb + (size_t)(bn + r)*K + k0 + scl,
              &Wl[buf][(wv*16)*32]);
    }
  };

  stage(0, 0);
  int buf = 0;
  for (int kt = 0; kt < nk; ++kt) {
    __syncthreads();                 // drains vmcnt -> buf ready
    if (kt+1 < nk) stage(buf^1, kt+1);
    bf16x8 av[4], wvv[NJ];
    #pragma unroll
    for (int i=0;i<4;i++) av[i] = *(const bf16x8*)&Al[buf][(wm + i*16 + fl)*32 + fk];
    #pragma unroll
    for (int j=0;j<NJ;j++) wvv[j] = *(const bf16x8*)&Wl[buf][(wn + j*16 + fl)*32 + fk];
    #pragma unroll
    for (int i=0;i<4;i++)
      #pragma unroll
      for (int j=0;j<NJ;j++)
        acc[i][j] = __builtin_amdgcn_mfma_f32_16x16x32_bf16(av[i], wvv[j], acc[i][j], 0, 0, 0);
    buf ^= 1;
  }

  // epilogue: C/D layout col=lane&15, row=(lane>>4)*4+reg
  #pragma unroll
  for (int j=0;j<NJ;j++){
    int gn = bn + wn + j*16 + fl;
    float bv = bias[gn];
    #pragma unroll
    for (int i=0;i<4;i++){
      #pragma unroll
      for (int r=0;r<4;r++){
        int gm = bm + wm + i*16 + (lane>>4)*4 + r;
        if (gm >= M) continue;
        float v = acc[i][j][r] + bv;
        if (ACT==1) v = fmaxf(v, 0.f);
        if (ACT==2) v = tanhf(v);
        if (RKM == 0) {
          if (res) v += res[(size_t)gm*ldc + gn];
          if (C)  C[(size_t)gm*ldc + gn] = v;
          if (Cb) Cb[(size_t)gm*ldc + gn] = f2bf(v);
        } else {
          size_t idx = (size_t)gm*512 + gn;
          float dt = rk.dtrow[gm];
          if (RKM == 1) {
            rk.acc[idx] = v;
            rk.y16[idx] = f2bf(rk.delta[idx] + rk.cy*dt*v);
          } else if (RKM == 2) {
            rk.acc[idx] += rk.wa*v;
            rk.y16[idx] = f2bf(rk.delta[idx] + rk.cy*dt*v);
          } else {
            float a = rk.acc[idx] + v;
            int srow = rk.srcrow[gm];
            rk.hin16[((size_t)srow+1)*512 + gn] =
                f2bf(rk.x[(size_t)srow*512 + gn] + dt*(1.f/6.f)*a);
            if ((srow & (TT-1)) == 0)            // fused zero of t=0 row (after-RK safe)
              rk.hin16[(size_t)srow*512 + gn] = 0;
          }
        }
      }
    }
  }
}

// ---------------- MFMA flash attention ----------------
template<int CAUSAL>
__global__ __launch_bounds__(256) void mattn_kernel(
    const unsigned short* __restrict__ QKV, unsigned short* __restrict__ O)
{
  __shared__ __align__(16) unsigned short Kl[32][72];
  __shared__ __align__(16) unsigned short Vt[64][36];
  __shared__ __align__(16) unsigned short Pl[4][16][40];
  const int b = blockIdx.x >> 3, h = blockIdx.x & 7;
  const int q0 = blockIdx.y * 64;
  const int tid = threadIdx.x;
  const int lane = tid & 63, wid = tid >> 6;
  const int lq = lane & 15, g = lane >> 4;
  const size_t rowbase = (size_t)b*TT;

  bf16x8 qf0, qf1;
  {
    const unsigned short* qp = QKV + (rowbase + q0 + wid*16 + lq)*1536 + h*64 + g*8;
    qf0 = *(const bf16x8*)qp;
    qf1 = *(const bf16x8*)(qp + 32);
  }
  f32x4 o[4];
  #pragma unroll
  for (int dt=0; dt<4; dt++) o[dt] = (f32x4){0.f,0.f,0.f,0.f};
  float mr[4] = {-1e30f,-1e30f,-1e30f,-1e30f};
  float Lr[4] = {0.f,0.f,0.f,0.f};

  const int nkt = CAUSAL ? (q0/32 + 2) : (TT/32);
  const int qwmax = q0 + wid*16 + 15;
  const int sr = tid >> 3, scol = (tid & 7) * 8;

  for (int kt = 0; kt < nkt; ++kt) {
    const int k0 = kt*32;
    __syncthreads();
    *(uint4*)&Kl[sr][scol] = *(const uint4*)(QKV + (rowbase + k0 + sr)*1536 + 512 + h*64 + scol);
    {
      uint4 vv = *(const uint4*)(QKV + (rowbase + k0 + sr)*1536 + 1024 + h*64 + scol);
      const unsigned short* vs = (const unsigned short*)&vv;
      #pragma unroll
      for (int i=0;i<8;i++) Vt[scol+i][sr] = vs[i];
    }
    __syncthreads();
    if (CAUSAL && k0 > qwmax) continue;

    f32x4 st0 = (f32x4){0.f,0.f,0.f,0.f}, st1 = (f32x4){0.f,0.f,0.f,0.f};
    {
      bf16x8 kb;
      kb = *(const bf16x8*)&Kl[lq][g*8];
      st0 = __builtin_amdgcn_mfma_f32_16x16x32_bf16(qf0, kb, st0, 0,0,0);
      kb = *(const bf16x8*)&Kl[lq][g*8+32];
      st0 = __builtin_amdgcn_mfma_f32_16x16x32_bf16(qf1, kb, st0, 0,0,0);
      kb = *(const bf16x8*)&Kl[16+lq][g*8];
      st1 = __builtin_amdgcn_mfma_f32_16x16x32_bf16(qf0, kb, st1, 0,0,0);
      kb = *(const bf16x8*)&Kl[16+lq][g*8+32];
      st1 = __builtin_amdgcn_mfma_f32_16x16x32_bf16(qf1, kb, st1, 0,0,0);
    }
    float s0[4], s1[4];
    #pragma unroll
    for (int r=0;r<4;r++){ s0[r] = st0[r]*0.125f; s1[r] = st1[r]*0.125f; }
    if (CAUSAL) {
      int kg0 = k0 + lq, kg1 = k0 + 16 + lq;
      #pragma unroll
      for (int r=0;r<4;r++){
        int qg = q0 + wid*16 + 4*g + r;
        if (kg0 > qg) s0[r] = -1e30f;
        if (kg1 > qg) s1[r] = -1e30f;
      }
    }
    #pragma unroll
    for (int r=0;r<4;r++){
      float v = fmaxf(s0[r], s1[r]);
      v = fmaxf(v, __shfl_xor(v,1));
      v = fmaxf(v, __shfl_xor(v,2));
      v = fmaxf(v, __shfl_xor(v,4));
      v = fmaxf(v, __shfl_xor(v,8));
      float mn = fmaxf(mr[r], v);
      float scl = expf(mr[r] - mn);
      mr[r] = mn;
      float p0 = expf(s0[r] - mn);
      float p1 = expf(s1[r] - mn);
      float lt = p0 + p1;
      lt += __shfl_xor(lt,1); lt += __shfl_xor(lt,2);
      lt += __shfl_xor(lt,4); lt += __shfl_xor(lt,8);
      Lr[r] = Lr[r]*scl + lt;
      o[0][r] *= scl; o[1][r] *= scl; o[2][r] *= scl; o[3][r] *= scl;
      Pl[wid][4*g+r][lq]    = f2bf(p0);
      Pl[wid][4*g+r][16+lq] = f2bf(p1);
    }
    bf16x8 ap = *(const bf16x8*)&Pl[wid][lq][g*8];
    #pragma unroll
    for (int dt=0; dt<4; dt++){
      bf16x4 a4 = *(const bf16x4*)&Vt[lq+16*dt][g*8];
      bf16x4 b4 = *(const bf16x4*)&Vt[lq+16*dt][g*8+4];
      bf16x8 vb = __builtin_shufflevector(a4, b4, 0,1,2,3,4,5,6,7);
      o[dt] = __builtin_amdgcn_mfma_f32_16x16x32_bf16(ap, vb, o[dt], 0,0,0);
    }
  }

  #pragma unroll
  for (int r=0;r<4;r++){
    float inv = 1.f / Lr[r];
    int qg = q0 + wid*16 + 4*g + r;
    unsigned short* op = O + (rowbase + qg)*DM + h*64 + lq;
    op[0]  = f2bf(o[0][r]*inv);
    op[16] = f2bf(o[1][r]*inv);
    op[32] = f2bf(o[2][r]*inv);
    op[48] = f2bf(o[3][r]*inv);
  }
}

// ---------------- GRU scan v4.2: tagged-value sync, J=16, dbuf hsp ----------------
// Same proven v4.1 protocol (poll IS the data load, relaxed agent atomics).
// Changes: 32 producers/batch (256 blocks = 1/CU -> smaller straggler max,
// less poll pressure) and double-buffered hsp (one barrier/step instead of two).
__global__ __launch_bounds__(256) void gru_scan_kernel(
    const float* __restrict__ gx,
    const float* __restrict__ whh,
    const float* __restrict__ bhh,
    float* __restrict__ Hs,
    unsigned short* __restrict__ Hsb,
    unsigned long long* hbuf)
{
  __shared__ float wlds[3][GRU_J][512];
  __shared__ float hsp[2][512];
  const int blk = blockIdx.x;
  const int b = blk & 7;           // batch -> XCD (round-robin dispatch)
  const int g = blk >> 3;          // slice 0..31
  const int j0 = g * GRU_J;
  const int tid = threadIdx.x;

  for (int idx = tid; idx < 3*GRU_J*512/4; idx += 256) {
    int f = idx*4;
    int gate = f >> 13;            // /(16*512)
    int rem = f & 8191;
    int jj = rem >> 9, k = rem & 511;
    *(float4*)&wlds[gate][jj][k] = *(const float4*)&whh[(size_t)(gate*512 + j0 + jj)*512 + k];
  }
  const int row = tid >> 4;        // dim 0..15 (16 lanes each)
  const int kl = tid & 15;
  const bool fin = (kl == 0);
  float bh0=0.f, bh1=0.f, bh2=0.f;
  if (fin) { bh0 = bhh[j0+row]; bh1 = bhh[512+j0+row]; bh2 = bhh[1024+j0+row]; }
  __syncthreads();

  for (int t = 0; t < TT; t++) {
    const int cur = t & 1;
    float g0=0.f, g1=0.f, g2=0.f;
    if (fin) {   // issued before poll; latency hides under the wait
      const float* gxr = gx + ((size_t)b*TT + t)*1536 + j0 + row;
      g0 = gxr[0]; g1 = gxr[512]; g2 = gxr[1024];
    }
    if (t == 0) {
      hsp[0][tid] = 0.f; hsp[0][tid+256] = 0.f;
    } else {
      const unsigned want = (unsigned)t;
      unsigned long long* src = hbuf + ((size_t)((t-1)&1)*BB + b)*512;
      unsigned long long u0, u1;
      for (;;) {
        u0 = __hip_atomic_load(src + tid,       __ATOMIC_RELAXED, __HIP_MEMORY_SCOPE_AGENT);
        u1 = __hip_atomic_load(src + tid + 256, __ATOMIC_RELAXED, __HIP_MEMORY_SCOPE_AGENT);
        if (((unsigned)(u0>>32) == want) & ((unsigned)(u1>>32) == want)) break;
        __builtin_amdgcn_s_sleep(1);
      }
      hsp[cur][tid]     = __uint_as_float((unsigned)u0);
      hsp[cur][tid+256] = __uint_as_float((unsigned)u1);
    }
    __syncthreads();   // hsp[cur] ready; next iter writes hsp[cur^1] (no trailing barrier)

    // dot: 16 lanes/dim, lane kl covers k = kl*4 + j*64 (2-way bank aliasing = free)
    float s0=0.f, s1=0.f, s2=0.f;
    #pragma unroll
    for (int j=0;j<8;j++){
      int k = kl*4 + j*64;
      float4 h4 = *(const float4*)&hsp[cur][k];
      float4 a = *(const float4*)&wlds[0][row][k];
      float4 c = *(const float4*)&wlds[1][row][k];
      float4 d = *(const float4*)&wlds[2][row][k];
      s0 += a.x*h4.x + a.y*h4.y + a.z*h4.z + a.w*h4.w;
      s1 += c.x*h4.x + c.y*h4.y + c.z*h4.z + c.w*h4.w;
      s2 += d.x*h4.x + d.y*h4.y + d.z*h4.z + d.w*h4.w;
    }
    #pragma unroll
    for (int off=1; off<16; off<<=1) {
      s0 += __shfl_xor(s0, off);
      s1 += __shfl_xor(s1, off);
      s2 += __shfl_xor(s2, off);
    }
    if (fin) {
      float r  = sigm_(g0 + s0 + bh0);
      float z  = sigm_(g1 + s1 + bh1);
      float n  = tanhf(g2 + r*(s2 + bh2));
      float hold = hsp[cur][j0 + row];
      float hnew = (1.f - z)*n + z*hold;
      size_t off = ((size_t)b*TT + t)*DM + j0 + row;
      Hs[off]  = hnew;
      Hsb[off] = f2bf(hnew);
      unsigned long long pk = ((unsigned long long)(unsigned)(t+1) << 32) | __float_as_uint(hnew);
      __hip_atomic_store(&hbuf[((size_t)cur*BB + b)*512 + j0 + row], pk,
                         __ATOMIC_RELAXED, __HIP_MEMORY_SCOPE_AGENT);
    }
  }
}

// ---------------- host ----------------
static RkArgs g_norm = {};

static void launch_bgemm(int act, int tn, const unsigned short* A16, const unsigned short* Wb,
                         const float* bias, const float* res, float* C, unsigned short* Cb,
                         int M, int N, int K, int ldc, hipStream_t stream)
{
  dim3 blk(256);
  if (tn == 128) {
    dim3 grid(N/128, (M+127)/128);
    switch(act){
      case 1: bgemm_kernel<1,128,0><<<grid,blk,0,stream>>>(A16,Wb,bias,res,C,Cb,M,N,K,ldc,g_norm); break;
      default: bgemm_kernel<0,128,0><<<grid,blk,0,stream>>>(A16,Wb,bias,res,C,Cb,M,N,K,ldc,g_norm); break;
    }
  } else {
    dim3 grid(N/64, (M+127)/128);
    switch(act){
      case 2: bgemm_kernel<2,64,0><<<grid,blk,0,stream>>>(A16,Wb,bias,res,C,Cb,M,N,K,ldc,g_norm); break;
      default: bgemm_kernel<0,64,0><<<grid,blk,0,stream>>>(A16,Wb,bias,res,C,Cb,M,N,K,ldc,g_norm); break;
    }
  }
}

extern "C" void kernel_launch(void* const* d_in, const int* in_sizes, int n_in,
                              void* d_out, int out_size, void* d_ws, size_t ws_size,
                              hipStream_t stream)
{
  (void)in_sizes; (void)n_in; (void)out_size; (void)ws_size;
  const float* x       = (const float*)d_in[0];
  const float* ts      = (const float*)d_in[1];
  const float* ode_w1  = (const float*)d_in[2];
  const float* ode_b1  = (const float*)d_in[3];
  const float* ode_w2  = (const float*)d_in[4];
  const float* ode_b2  = (const float*)d_in[5];
  const float* gru_wih = (const float*)d_in[6];
  const float* gru_whh = (const float*)d_in[7];
  const float* gru_bih = (const float*)d_in[8];
  const float* gru_bhh = (const float*)d_in[9];
  const float* te_a    = (const float*)d_in[10];
  const float* te_b    = (const float*)d_in[11];
  const float* t_in_w  = (const float*)d_in[12];
  const float* t_in_b  = (const float*)d_in[13];
  const float* t_out_w = (const float*)d_in[14];
  const float* t_out_b = (const float*)d_in[15];
  const float* t_ln1_w = (const float*)d_in[16];
  const float* t_ln1_b = (const float*)d_in[17];
  const float* t_ln2_w = (const float*)d_in[18];
  const float* t_ln2_b = (const float*)d_in[19];
  const float* t_ff1_w = (const float*)d_in[20];
  const float* t_ff1_b = (const float*)d_in[21];
  const float* t_ff2_w = (const float*)d_in[22];
  const float* t_ff2_b = (const float*)d_in[23];
  const float* t_lnf_w = (const float*)d_in[24];
  const float* t_lnf_b = (const float*)d_in[25];
  const float* ca_in_w = (const float*)d_in[26];
  const float* ca_in_b = (const float*)d_in[27];
  const float* ca_out_w= (const float*)d_in[28];
  const float* ca_out_b= (const float*)d_in[29];
  const float* ca_lin_w= (const float*)d_in[30];
  const float* ca_lin_b= (const float*)d_in[31];
  const float* ca_ln_w = (const float*)d_in[32];
  const float* ca_ln_b = (const float*)d_in[33];

  float* ws = (float*)d_ws;
  const size_t SZ = (size_t)ROWS * DM;
  // f32 pool
  float* deltab = ws + 0*SZ;
  float* accb   = ws + 1*SZ;
  float* fcur   = ws + 2*SZ;                 // ca pre-LN
  float* gx     = ws + 3*SZ;                 // 3*SZ
  float* zbuf   = ws + 6*SZ;
  float* hsb    = ws + 7*SZ;
  unsigned long long* hbuf = (unsigned long long*)(ws + 8*SZ);   // 64KB tagged
  float* dtrow  = ws + 8*SZ + 16384;                             // 8184 f32
  int*   srcrow = (int*)(ws + 8*SZ + 16384 + 8192);              // 8184 i32
  // bf16 pool
  unsigned short* u16 = (unsigned short*)(ws + 8*SZ + 16384 + 16384);
  unsigned short* delta16 = u16 + 0*SZ;
  unsigned short* y16     = u16 + 1*SZ;
  unsigned short* t16     = u16 + 2*SZ;
  unsigned short* hs16    = u16 + 3*SZ;
  unsigned short* ff1b16  = u16 + 4*SZ;      // 4*SZ; qkv16 aliases
  unsigned short* qkv16   = ff1b16;
  unsigned short* ao16    = delta16;
  unsigned short* hin16   = y16;
  unsigned short* cao16   = y16;
  unsigned short* ln16    = t16;
  // weights (one fused cast; offsets in elems = 4*float4-off)
  unsigned short* wb = u16 + 8*SZ;
  unsigned short* wb_ode1 = wb + 0;
  unsigned short* wb_ode2 = wb + 262144;
  unsigned short* wb_gwih = wb + 524288;
  unsigned short* wb_tin  = wb + 1310720;
  unsigned short* wb_tout = wb + 2883584;
  unsigned short* wb_ff1  = wb + 3407872;
  unsigned short* wb_ff2  = wb + 5505024;
  unsigned short* wb_cain = wb + 7602176;
  unsigned short* wb_caout= wb + 8388608;
  unsigned short* wb_calin= wb + 8650752;

  castall_kernel<<<(2228224+255)/256, 256, 0, stream>>>(
      ode_w1, ode_w2, gru_wih, t_in_w, t_out_w, t_ff1_w, t_ff2_w,
      ca_in_w, ca_out_w, ca_lin_w, wb);

  // ---- ODE (RK4), rk+states+zero fused into ode2 epilogues ----
  delta_kernel<<<ROWS1*DM/256, 256, 0, stream>>>(x, ts, deltab, delta16, dtrow, srcrow);
  RkArgs rk; rk.delta = deltab; rk.acc = accb; rk.y16 = y16;
  rk.dtrow = dtrow; rk.srcrow = srcrow; rk.x = x; rk.hin16 = hin16;
  const unsigned short* yin16 = delta16;
  const float was[4] = {1.f, 2.f, 2.f, 1.f};
  const float cys[4] = {0.5f, 0.5f, 1.f, 0.f};
  for (int s4 = 0; s4 < 4; s4++) {
    launch_bgemm(2, 64, yin16, wb_ode1, ode_b1, nullptr, nullptr, t16, ROWS1, 512, 512, 512, stream);
    rk.wa = was[s4]; rk.cy = cys[s4];
    dim3 grid(512/64, (ROWS1+127)/128), blk(256);
    if (s4 == 0)
      bgemm_kernel<0,64,1><<<grid,blk,0,stream>>>(t16, wb_ode2, ode_b2, nullptr, nullptr, nullptr, ROWS1, 512, 512, 512, rk);
    else if (s4 < 3)
      bgemm_kernel<0,64,2><<<grid,blk,0,stream>>>(t16, wb_ode2, ode_b2, nullptr, nullptr, nullptr, ROWS1, 512, 512, 512, rk);
    else
      bgemm_kernel<0,64,3><<<grid,blk,0,stream>>>(t16, wb_ode2, ode_b2, nullptr, nullptr, nullptr, ROWS1, 512, 512, 512, rk);
    yin16 = y16;
  }

  // ---- GRU ----
  launch_bgemm(0, 128, hin16, wb_gwih, gru_bih, nullptr, gx, nullptr, ROWS, 1536, 512, 1536, stream);
  gru_scan_kernel<<<GRU_BLK, 256, 0, stream>>>(gx, gru_whh, gru_bhh, hsb, hs16, hbuf);

  // ---- transformer (2 layers, pre-norm, causal); timeenc fused into l0 ln1 ----
  for (int l = 0; l < 2; l++) {
    if (l == 0)
      ln_kernel<1,1><<<ROWS,256,0,stream>>>(x, t_ln1_w, t_ln1_b, ln16, ts, te_a, te_b, zbuf);
    else
      ln_kernel<1,0><<<ROWS,256,0,stream>>>(zbuf, t_ln1_w + 512, t_ln1_b + 512, ln16,
                                            nullptr, nullptr, nullptr, nullptr);
    launch_bgemm(0, 128, ln16, wb_tin + (size_t)l*1536*512, t_in_b + l*1536, nullptr, nullptr, qkv16, ROWS, 1536, 512, 1536, stream);
    mattn_kernel<1><<<dim3(64, TT/64), 256, 0, stream>>>(qkv16, ao16);
    launch_bgemm(0, 64, ao16, wb_tout + (size_t)l*512*512, t_out_b + l*512, zbuf, zbuf, nullptr, ROWS, 512, 512, 512, stream);
    ln_kernel<1,0><<<ROWS,256,0,stream>>>(zbuf, t_ln2_w + l*512, t_ln2_b + l*512, ln16,
                                          nullptr, nullptr, nullptr, nullptr);
    launch_bgemm(1, 128, ln16, wb_ff1 + (size_t)l*2048*512, t_ff1_b + l*2048, nullptr, nullptr, ff1b16, ROWS, 2048, 512, 2048, stream);
    launch_bgemm(0, 64, ff1b16, wb_ff2 + (size_t)l*512*2048, t_ff2_b + l*512, zbuf, zbuf, nullptr, ROWS, 512, 2048, 512, stream);
  }
  ln_kernel<1,0><<<ROWS,256,0,stream>>>(zbuf, t_lnf_w, t_lnf_b, ln16,
                                        nullptr, nullptr, nullptr, nullptr);

  // ---- cross attention ----
  launch_bgemm(0, 64,  hs16, wb_cain,           ca_in_b,       nullptr, nullptr, qkv16,       ROWS,  512, 512, 1536, stream);
  launch_bgemm(0, 128, ln16, wb_cain + 512*512, ca_in_b + 512, nullptr, nullptr, qkv16 + 512, ROWS, 1024, 512, 1536, stream);
  mattn_kernel<0><<<dim3(64, TT/64), 256, 0, stream>>>(qkv16, ao16);
  launch_bgemm(0, 64, ao16, wb_caout, ca_out_b, nullptr, nullptr, cao16, ROWS, 512, 512, 512, stream);
  launch_bgemm(0, 64, cao16, wb_calin, ca_lin_b, hsb, fcur, nullptr, ROWS, 512, 512, 512, stream);
  ln_kernel<0,0><<<ROWS,256,0,stream>>>(fcur, ca_ln_w, ca_ln_b, (float*)d_out,
                                        nullptr, nullptr, nullptr, nullptr);
}

// Round 12
// 2714.669 us; speedup vs baseline: 2.3490x; 1.0308x over previous
//
#include <hip/hip_runtime.h>
#include <math.h>

#define BB 8
#define TT 1024
#define DM 512
#define ROWS (BB*TT)     // 8192
#define ROWS1 (BB*(TT-1))// 8184
#define GRU_J 16         // hidden dims per block
#define GRU_GPB 32       // blocks per batch
#define GRU_BLK (BB*GRU_GPB)  // 256 blocks = 1/CU

typedef __attribute__((ext_vector_type(4))) float f32x4;
typedef __attribute__((ext_vector_type(8))) short bf16x8;
typedef __attribute__((ext_vector_type(4))) short bf16x4;

#define GLOAD16(g, l) __builtin_amdgcn_global_load_lds( \
    (const __attribute__((address_space(1))) void*)(g), \
    (__attribute__((address_space(3))) void*)(l), 16, 0, 0)

struct RkArgs {
  const float* delta; float* acc; unsigned short* y16;
  const float* dtrow; const int* srcrow;
  const float* x; unsigned short* hin16;
  float wa, cy;
};

__device__ __forceinline__ float sigm_(float v){ return 1.f/(1.f+expf(-v)); }

__device__ __forceinline__ unsigned short f2bf(float f){
  unsigned u = __float_as_uint(f);
  return (unsigned short)((u + 0x7FFFu + ((u>>16)&1u)) >> 16);
}

// ---------------- fused weight cast (all 10 weights, 1 launch) ----------------
__global__ __launch_bounds__(256) void castall_kernel(
    const float* w0, const float* w1, const float* w2, const float* w3,
    const float* w4, const float* w5, const float* w6, const float* w7,
    const float* w8, const float* w9, unsigned short* __restrict__ o)
{
  int i = blockIdx.x*256 + threadIdx.x;           // in float4 units
  if (i >= 2228224) return;
  const float* src; int off;
  if      (i <   65536){ src=w0; off=0; }
  else if (i <  131072){ src=w1; off=65536; }
  else if (i <  327680){ src=w2; off=131072; }
  else if (i <  720896){ src=w3; off=327680; }
  else if (i <  851968){ src=w4; off=720896; }
  else if (i < 1376256){ src=w5; off=851968; }
  else if (i < 1900544){ src=w6; off=1376256; }
  else if (i < 2097152){ src=w7; off=1900544; }
  else if (i < 2162688){ src=w8; off=2097152; }
  else                 { src=w9; off=2162688; }
  float4 v = ((const float4*)src)[i - off];
  ushort4 u;
  u.x = f2bf(v.x); u.y = f2bf(v.y); u.z = f2bf(v.z); u.w = f2bf(v.w);
  ((ushort4*)o)[i] = u;
}

// ---------------- elementwise ----------------
__global__ __launch_bounds__(256) void delta_kernel(const float* __restrict__ x,
    const float* __restrict__ ts, float* __restrict__ delta,
    unsigned short* __restrict__ delta16,
    float* __restrict__ dtrow, int* __restrict__ srcrow)
{
  size_t i = (size_t)blockIdx.x*256 + threadIdx.x;
  int d = (int)(i & (DM-1));
  int r = (int)(i >> 9);
  int b = r / (TT-1), ii = r % (TT-1);
  float dt = ts[b*TT+ii+1] - ts[b*TT+ii];
  float x1 = x[((size_t)b*TT+ii+1)*DM + d];
  float x0 = x[((size_t)b*TT+ii)*DM + d];
  float v = (x1 - x0) / dt;
  delta[i] = v;
  delta16[i] = f2bf(v);
  if (d == 0) { dtrow[r] = dt; srcrow[r] = b*TT + ii; }
}

// ---------------- LayerNorm (block per row, D=512) ----------------
// TE=1: input = x + time-encoding (fused timeenc, layer-0 ln1); also writes zout f32.
template<int BF, int TE>
__global__ __launch_bounds__(256) void ln_kernel(const float* __restrict__ x,
    const float* __restrict__ w, const float* __restrict__ b,
    void* __restrict__ outp,
    const float* ts, const float* te_a, const float* te_b, float* zout)
{
  int row = blockIdx.x;
  int tid = threadIdx.x;
  const float* xr = x + (size_t)row*DM;
  float2 v = *(const float2*)(xr + tid*2);
  if (TE) {
    float t = ts[row];
    int d0 = tid*2;
    int fi = d0 >> 2;
    float fr = expf(-(float)fi * 0.061606661f) * 1.5707964f;
    float ph = t * fr;
    float tm0 = ((d0 & 3) == 0) ? sinf(ph) : cosf(ph);
    float tm1 = t*te_a[tid] + te_b[tid];
    v.x += tm0; v.y += tm1;
    *(float2*)(zout + (size_t)row*DM + tid*2) = v;
  }
  float s = v.x+v.y, sq = v.x*v.x + v.y*v.y;
  #pragma unroll
  for (int off=1; off<64; off<<=1){ s += __shfl_xor(s,off); sq += __shfl_xor(sq,off); }
  __shared__ float rs[4], rq[4];
  int wid = tid>>6;
  if ((tid&63)==0){ rs[wid]=s; rq[wid]=sq; }
  __syncthreads();
  s = rs[0]+rs[1]+rs[2]+rs[3];
  sq = rq[0]+rq[1]+rq[2]+rq[3];
  float mean = s*(1.f/DM);
  float var = sq*(1.f/DM) - mean*mean;
  float inv = rsqrtf(var + 1e-5f);
  float2 wv = *(const float2*)(w + tid*2);
  float2 bv = *(const float2*)(b + tid*2);
  float ox = (v.x-mean)*inv*wv.x + bv.x;
  float oy = (v.y-mean)*inv*wv.y + bv.y;
  if (BF) {
    ushort2 u; u.x = f2bf(ox); u.y = f2bf(oy);
    *(ushort2*)((unsigned short*)outp + (size_t)row*DM + tid*2) = u;
  } else {
    float2 o; o.x = ox; o.y = oy;
    *(float2*)((float*)outp + (size_t)row*DM + tid*2) = o;
  }
}

// ---------------- bf16 MFMA GEMM, global_load_lds staging ----------------
// TN 128/64/32. TN=32 -> grid N/32 (4 blocks/CU at N=512: latency hiding for
// the thin-N GEMMs). RKM: 0 none, 1 RK-init, 2 RK-mid, 3 RK-final (ldc==512).
template<int ACT, int TN, int RKM>
__global__ __launch_bounds__(256) void bgemm_kernel(
    const unsigned short* __restrict__ A16, const unsigned short* __restrict__ Wb,
    const float* __restrict__ bias, const float* res,
    float* C, unsigned short* Cb, int M, int N, int K, int ldc, RkArgs rk)
{
  const int NJ = (TN+31)/32;
  __shared__ __align__(16) unsigned short Al[2][128*32];
  __shared__ __align__(16) unsigned short Wl[2][TN*32];
  const int bm = blockIdx.y*128, bn = blockIdx.x*TN;
  const int tid = threadIdx.x;
  const int lane = tid & 63, wv = tid >> 6;
  const int wm = (wv&1)*64, wn = (wv>>1)*(TN/2);
  const int fl = lane & 15, fk = (lane>>4)*8;
  const int srw = lane >> 2;         // row within 16-row group
  const int scl = (lane & 3)*8;      // 16B slot (elems)
  f32x4 acc[4][NJ];
  #pragma unroll
  for (int i=0;i<4;i++)
    #pragma unroll
    for (int j=0;j<NJ;j++) acc[i][j] = (f32x4){0.f,0.f,0.f,0.f};

  const int nk = K >> 5;

  auto stage = [&](int buf, int kt){
    int k0 = kt*32;
    #pragma unroll
    for (int j=0;j<2;j++){
      int r = wv*32 + j*16 + srw;
      GLOAD16(A16 + (size_t)(bm + r)*K + k0 + scl,
              &Al[buf][(wv*32 + j*16)*32]);
    }
    if (TN == 128) {
      #pragma unroll
      for (int j=0;j<2;j++){
        int r = wv*32 + j*16 + srw;
        GLOAD16(Wb + (size_t)(bn + r)*K + k0 + scl,
                &Wl[buf][(wv*32 + j*16)*32]);
      }
    } else if (TN == 64) {
      int r = wv*16 + srw;
      GLOAD16(Wb + (size_t)(bn + r)*K + k0 + scl,
              &Wl[buf][(wv*16)*32]);
    } else {                       // TN==32: only waves 0-1 stage W
      if (wv < 2) {
        int r = wv*16 + srw;
        GLOAD16(Wb + (size_t)(bn + r)*K + k0 + scl,
                &Wl[buf][(wv*16)*32]);
      }
    }
  };

  stage(0, 0);
  int buf = 0;
  for (int kt = 0; kt < nk; ++kt) {
    __syncthreads();                 // drains vmcnt -> buf ready
    if (kt+1 < nk) stage(buf^1, kt+1);
    bf16x8 av[4], wvv[NJ];
    #pragma unroll
    for (int i=0;i<4;i++) av[i] = *(const bf16x8*)&Al[buf][(wm + i*16 + fl)*32 + fk];
    #pragma unroll
    for (int j=0;j<NJ;j++) wvv[j] = *(const bf16x8*)&Wl[buf][(wn + j*16 + fl)*32 + fk];
    #pragma unroll
    for (int i=0;i<4;i++)
      #pragma unroll
      for (int j=0;j<NJ;j++)
        acc[i][j] = __builtin_amdgcn_mfma_f32_16x16x32_bf16(av[i], wvv[j], acc[i][j], 0, 0, 0);
    buf ^= 1;
  }

  // epilogue: C/D layout col=lane&15, row=(lane>>4)*4+reg
  #pragma unroll
  for (int j=0;j<NJ;j++){
    int gn = bn + wn + j*16 + fl;
    float bv = bias[gn];
    #pragma unroll
    for (int i=0;i<4;i++){
      #pragma unroll
      for (int r=0;r<4;r++){
        int gm = bm + wm + i*16 + (lane>>4)*4 + r;
        if (gm >= M) continue;
        float v = acc[i][j][r] + bv;
        if (ACT==1) v = fmaxf(v, 0.f);
        if (ACT==2) v = tanhf(v);
        if (RKM == 0) {
          if (res) v += res[(size_t)gm*ldc + gn];
          if (C)  C[(size_t)gm*ldc + gn] = v;
          if (Cb) Cb[(size_t)gm*ldc + gn] = f2bf(v);
        } else {
          size_t idx = (size_t)gm*512 + gn;
          float dt = rk.dtrow[gm];
          if (RKM == 1) {
            rk.acc[idx] = v;
            rk.y16[idx] = f2bf(rk.delta[idx] + rk.cy*dt*v);
          } else if (RKM == 2) {
            rk.acc[idx] += rk.wa*v;
            rk.y16[idx] = f2bf(rk.delta[idx] + rk.cy*dt*v);
          } else {
            float a = rk.acc[idx] + v;
            int srow = rk.srcrow[gm];
            rk.hin16[((size_t)srow+1)*512 + gn] =
                f2bf(rk.x[(size_t)srow*512 + gn] + dt*(1.f/6.f)*a);
            if ((srow & (TT-1)) == 0)            // fused zero of t=0 row (after-RK safe)
              rk.hin16[(size_t)srow*512 + gn] = 0;
          }
        }
      }
    }
  }
}

// ---------------- MFMA flash attention ----------------
template<int CAUSAL>
__global__ __launch_bounds__(256) void mattn_kernel(
    const unsigned short* __restrict__ QKV, unsigned short* __restrict__ O)
{
  __shared__ __align__(16) unsigned short Kl[32][72];
  __shared__ __align__(16) unsigned short Vt[64][36];
  __shared__ __align__(16) unsigned short Pl[4][16][40];
  const int b = blockIdx.x >> 3, h = blockIdx.x & 7;
  const int q0 = blockIdx.y * 64;
  const int tid = threadIdx.x;
  const int lane = tid & 63, wid = tid >> 6;
  const int lq = lane & 15, g = lane >> 4;
  const size_t rowbase = (size_t)b*TT;

  bf16x8 qf0, qf1;
  {
    const unsigned short* qp = QKV + (rowbase + q0 + wid*16 + lq)*1536 + h*64 + g*8;
    qf0 = *(const bf16x8*)qp;
    qf1 = *(const bf16x8*)(qp + 32);
  }
  f32x4 o[4];
  #pragma unroll
  for (int dt=0; dt<4; dt++) o[dt] = (f32x4){0.f,0.f,0.f,0.f};
  float mr[4] = {-1e30f,-1e30f,-1e30f,-1e30f};
  float Lr[4] = {0.f,0.f,0.f,0.f};

  const int nkt = CAUSAL ? (q0/32 + 2) : (TT/32);
  const int qwmax = q0 + wid*16 + 15;
  const int sr = tid >> 3, scol = (tid & 7) * 8;

  for (int kt = 0; kt < nkt; ++kt) {
    const int k0 = kt*32;
    __syncthreads();
    *(uint4*)&Kl[sr][scol] = *(const uint4*)(QKV + (rowbase + k0 + sr)*1536 + 512 + h*64 + scol);
    {
      uint4 vv = *(const uint4*)(QKV + (rowbase + k0 + sr)*1536 + 1024 + h*64 + scol);
      const unsigned short* vs = (const unsigned short*)&vv;
      #pragma unroll
      for (int i=0;i<8;i++) Vt[scol+i][sr] = vs[i];
    }
    __syncthreads();
    if (CAUSAL && k0 > qwmax) continue;

    f32x4 st0 = (f32x4){0.f,0.f,0.f,0.f}, st1 = (f32x4){0.f,0.f,0.f,0.f};
    {
      bf16x8 kb;
      kb = *(const bf16x8*)&Kl[lq][g*8];
      st0 = __builtin_amdgcn_mfma_f32_16x16x32_bf16(qf0, kb, st0, 0,0,0);
      kb = *(const bf16x8*)&Kl[lq][g*8+32];
      st0 = __builtin_amdgcn_mfma_f32_16x16x32_bf16(qf1, kb, st0, 0,0,0);
      kb = *(const bf16x8*)&Kl[16+lq][g*8];
      st1 = __builtin_amdgcn_mfma_f32_16x16x32_bf16(qf0, kb, st1, 0,0,0);
      kb = *(const bf16x8*)&Kl[16+lq][g*8+32];
      st1 = __builtin_amdgcn_mfma_f32_16x16x32_bf16(qf1, kb, st1, 0,0,0);
    }
    float s0[4], s1[4];
    #pragma unroll
    for (int r=0;r<4;r++){ s0[r] = st0[r]*0.125f; s1[r] = st1[r]*0.125f; }
    if (CAUSAL) {
      int kg0 = k0 + lq, kg1 = k0 + 16 + lq;
      #pragma unroll
      for (int r=0;r<4;r++){
        int qg = q0 + wid*16 + 4*g + r;
        if (kg0 > qg) s0[r] = -1e30f;
        if (kg1 > qg) s1[r] = -1e30f;
      }
    }
    #pragma unroll
    for (int r=0;r<4;r++){
      float v = fmaxf(s0[r], s1[r]);
      v = fmaxf(v, __shfl_xor(v,1));
      v = fmaxf(v, __shfl_xor(v,2));
      v = fmaxf(v, __shfl_xor(v,4));
      v = fmaxf(v, __shfl_xor(v,8));
      float mn = fmaxf(mr[r], v);
      float scl = expf(mr[r] - mn);
      mr[r] = mn;
      float p0 = expf(s0[r] - mn);
      float p1 = expf(s1[r] - mn);
      float lt = p0 + p1;
      lt += __shfl_xor(lt,1); lt += __shfl_xor(lt,2);
      lt += __shfl_xor(lt,4); lt += __shfl_xor(lt,8);
      Lr[r] = Lr[r]*scl + lt;
      o[0][r] *= scl; o[1][r] *= scl; o[2][r] *= scl; o[3][r] *= scl;
      Pl[wid][4*g+r][lq]    = f2bf(p0);
      Pl[wid][4*g+r][16+lq] = f2bf(p1);
    }
    bf16x8 ap = *(const bf16x8*)&Pl[wid][lq][g*8];
    #pragma unroll
    for (int dt=0; dt<4; dt++){
      bf16x4 a4 = *(const bf16x4*)&Vt[lq+16*dt][g*8];
      bf16x4 b4 = *(const bf16x4*)&Vt[lq+16*dt][g*8+4];
      bf16x8 vb = __builtin_shufflevector(a4, b4, 0,1,2,3,4,5,6,7);
      o[dt] = __builtin_amdgcn_mfma_f32_16x16x32_bf16(ap, vb, o[dt], 0,0,0);
    }
  }

  #pragma unroll
  for (int r=0;r<4;r++){
    float inv = 1.f / Lr[r];
    int qg = q0 + wid*16 + 4*g + r;
    unsigned short* op = O + (rowbase + qg)*DM + h*64 + lq;
    op[0]  = f2bf(o[0][r]*inv);
    op[16] = f2bf(o[1][r]*inv);
    op[32] = f2bf(o[2][r]*inv);
    op[48] = f2bf(o[3][r]*inv);
  }
}

// ---------------- GRU scan v4.2: tagged-value sync, J=16, dbuf hsp ----------------
__global__ __launch_bounds__(256) void gru_scan_kernel(
    const float* __restrict__ gx,
    const float* __restrict__ whh,
    const float* __restrict__ bhh,
    float* __restrict__ Hs,
    unsigned short* __restrict__ Hsb,
    unsigned long long* hbuf)
{
  __shared__ float wlds[3][GRU_J][512];
  __shared__ float hsp[2][512];
  const int blk = blockIdx.x;
  const int b = blk & 7;           // batch -> XCD (round-robin dispatch)
  const int g = blk >> 3;          // slice 0..31
  const int j0 = g * GRU_J;
  const int tid = threadIdx.x;

  for (int idx = tid; idx < 3*GRU_J*512/4; idx += 256) {
    int f = idx*4;
    int gate = f >> 13;            // /(16*512)
    int rem = f & 8191;
    int jj = rem >> 9, k = rem & 511;
    *(float4*)&wlds[gate][jj][k] = *(const float4*)&whh[(size_t)(gate*512 + j0 + jj)*512 + k];
  }
  const int row = tid >> 4;        // dim 0..15 (16 lanes each)
  const int kl = tid & 15;
  const bool fin = (kl == 0);
  float bh0=0.f, bh1=0.f, bh2=0.f;
  if (fin) { bh0 = bhh[j0+row]; bh1 = bhh[512+j0+row]; bh2 = bhh[1024+j0+row]; }
  __syncthreads();

  for (int t = 0; t < TT; t++) {
    const int cur = t & 1;
    float g0=0.f, g1=0.f, g2=0.f;
    if (fin) {   // issued before poll; latency hides under the wait
      const float* gxr = gx + ((size_t)b*TT + t)*1536 + j0 + row;
      g0 = gxr[0]; g1 = gxr[512]; g2 = gxr[1024];
    }
    if (t == 0) {
      hsp[0][tid] = 0.f; hsp[0][tid+256] = 0.f;
    } else {
      const unsigned want = (unsigned)t;
      unsigned long long* src = hbuf + ((size_t)((t-1)&1)*BB + b)*512;
      unsigned long long u0, u1;
      for (;;) {
        u0 = __hip_atomic_load(src + tid,       __ATOMIC_RELAXED, __HIP_MEMORY_SCOPE_AGENT);
        u1 = __hip_atomic_load(src + tid + 256, __ATOMIC_RELAXED, __HIP_MEMORY_SCOPE_AGENT);
        if (((unsigned)(u0>>32) == want) & ((unsigned)(u1>>32) == want)) break;
        __builtin_amdgcn_s_sleep(1);
      }
      hsp[cur][tid]     = __uint_as_float((unsigned)u0);
      hsp[cur][tid+256] = __uint_as_float((unsigned)u1);
    }
    __syncthreads();   // hsp[cur] ready; next iter writes hsp[cur^1]

    float s0=0.f, s1=0.f, s2=0.f;
    #pragma unroll
    for (int j=0;j<8;j++){
      int k = kl*4 + j*64;
      float4 h4 = *(const float4*)&hsp[cur][k];
      float4 a = *(const float4*)&wlds[0][row][k];
      float4 c = *(const float4*)&wlds[1][row][k];
      float4 d = *(const float4*)&wlds[2][row][k];
      s0 += a.x*h4.x + a.y*h4.y + a.z*h4.z + a.w*h4.w;
      s1 += c.x*h4.x + c.y*h4.y + c.z*h4.z + c.w*h4.w;
      s2 += d.x*h4.x + d.y*h4.y + d.z*h4.z + d.w*h4.w;
    }
    #pragma unroll
    for (int off=1; off<16; off<<=1) {
      s0 += __shfl_xor(s0, off);
      s1 += __shfl_xor(s1, off);
      s2 += __shfl_xor(s2, off);
    }
    if (fin) {
      float r  = sigm_(g0 + s0 + bh0);
      float z  = sigm_(g1 + s1 + bh1);
      float n  = tanhf(g2 + r*(s2 + bh2));
      float hold = hsp[cur][j0 + row];
      float hnew = (1.f - z)*n + z*hold;
      size_t off = ((size_t)b*TT + t)*DM + j0 + row;
      Hs[off]  = hnew;
      Hsb[off] = f2bf(hnew);
      unsigned long long pk = ((unsigned long long)(unsigned)(t+1) << 32) | __float_as_uint(hnew);
      __hip_atomic_store(&hbuf[((size_t)cur*BB + b)*512 + j0 + row], pk,
                         __ATOMIC_RELAXED, __HIP_MEMORY_SCOPE_AGENT);
    }
  }
}

// ---------------- host ----------------
static RkArgs g_norm = {};

static void launch_bgemm(int act, int tn, const unsigned short* A16, const unsigned short* Wb,
                         const float* bias, const float* res, float* C, unsigned short* Cb,
                         int M, int N, int K, int ldc, hipStream_t stream)
{
  dim3 blk(256);
  if (tn == 128) {
    dim3 grid(N/128, (M+127)/128);
    switch(act){
      case 1: bgemm_kernel<1,128,0><<<grid,blk,0,stream>>>(A16,Wb,bias,res,C,Cb,M,N,K,ldc,g_norm); break;
      default: bgemm_kernel<0,128,0><<<grid,blk,0,stream>>>(A16,Wb,bias,res,C,Cb,M,N,K,ldc,g_norm); break;
    }
  } else {
    dim3 grid(N/32, (M+127)/128);
    switch(act){
      case 2: bgemm_kernel<2,32,0><<<grid,blk,0,stream>>>(A16,Wb,bias,res,C,Cb,M,N,K,ldc,g_norm); break;
      default: bgemm_kernel<0,32,0><<<grid,blk,0,stream>>>(A16,Wb,bias,res,C,Cb,M,N,K,ldc,g_norm); break;
    }
  }
}

extern "C" void kernel_launch(void* const* d_in, const int* in_sizes, int n_in,
                              void* d_out, int out_size, void* d_ws, size_t ws_size,
                              hipStream_t stream)
{
  (void)in_sizes; (void)n_in; (void)out_size; (void)ws_size;
  const float* x       = (const float*)d_in[0];
  const float* ts      = (const float*)d_in[1];
  const float* ode_w1  = (const float*)d_in[2];
  const float* ode_b1  = (const float*)d_in[3];
  const float* ode_w2  = (const float*)d_in[4];
  const float* ode_b2  = (const float*)d_in[5];
  const float* gru_wih = (const float*)d_in[6];
  const float* gru_whh = (const float*)d_in[7];
  const float* gru_bih = (const float*)d_in[8];
  const float* gru_bhh = (const float*)d_in[9];
  const float* te_a    = (const float*)d_in[10];
  const float* te_b    = (const float*)d_in[11];
  const float* t_in_w  = (const float*)d_in[12];
  const float* t_in_b  = (const float*)d_in[13];
  const float* t_out_w = (const float*)d_in[14];
  const float* t_out_b = (const float*)d_in[15];
  const float* t_ln1_w = (const float*)d_in[16];
  const float* t_ln1_b = (const float*)d_in[17];
  const float* t_ln2_w = (const float*)d_in[18];
  const float* t_ln2_b = (const float*)d_in[19];
  const float* t_ff1_w = (const float*)d_in[20];
  const float* t_ff1_b = (const float*)d_in[21];
  const float* t_ff2_w = (const float*)d_in[22];
  const float* t_ff2_b = (const float*)d_in[23];
  const float* t_lnf_w = (const float*)d_in[24];
  const float* t_lnf_b = (const float*)d_in[25];
  const float* ca_in_w = (const float*)d_in[26];
  const float* ca_in_b = (const float*)d_in[27];
  const float* ca_out_w= (const float*)d_in[28];
  const float* ca_out_b= (const float*)d_in[29];
  const float* ca_lin_w= (const float*)d_in[30];
  const float* ca_lin_b= (const float*)d_in[31];
  const float* ca_ln_w = (const float*)d_in[32];
  const float* ca_ln_b = (const float*)d_in[33];

  float* ws = (float*)d_ws;
  const size_t SZ = (size_t)ROWS * DM;
  // f32 pool
  float* deltab = ws + 0*SZ;
  float* accb   = ws + 1*SZ;
  float* fcur   = ws + 2*SZ;                 // ca pre-LN
  float* gx     = ws + 3*SZ;                 // 3*SZ
  float* zbuf   = ws + 6*SZ;
  float* hsb    = ws + 7*SZ;
  unsigned long long* hbuf = (unsigned long long*)(ws + 8*SZ);   // 64KB tagged
  float* dtrow  = ws + 8*SZ + 16384;                             // 8184 f32
  int*   srcrow = (int*)(ws + 8*SZ + 16384 + 8192);              // 8184 i32
  // bf16 pool
  unsigned short* u16 = (unsigned short*)(ws + 8*SZ + 16384 + 16384);
  unsigned short* delta16 = u16 + 0*SZ;
  unsigned short* y16     = u16 + 1*SZ;
  unsigned short* t16     = u16 + 2*SZ;
  unsigned short* hs16    = u16 + 3*SZ;
  unsigned short* ff1b16  = u16 + 4*SZ;      // 4*SZ; qkv16 aliases
  unsigned short* qkv16   = ff1b16;
  unsigned short* ao16    = delta16;
  unsigned short* hin16   = y16;
  unsigned short* cao16   = y16;
  unsigned short* ln16    = t16;
  // weights (one fused cast; offsets in elems = 4*float4-off)
  unsigned short* wb = u16 + 8*SZ;
  unsigned short* wb_ode1 = wb + 0;
  unsigned short* wb_ode2 = wb + 262144;
  unsigned short* wb_gwih = wb + 524288;
  unsigned short* wb_tin  = wb + 1310720;
  unsigned short* wb_tout = wb + 2883584;
  unsigned short* wb_ff1  = wb + 3407872;
  unsigned short* wb_ff2  = wb + 5505024;
  unsigned short* wb_cain = wb + 7602176;
  unsigned short* wb_caout= wb + 8388608;
  unsigned short* wb_calin= wb + 8650752;

  castall_kernel<<<(2228224+255)/256, 256, 0, stream>>>(
      ode_w1, ode_w2, gru_wih, t_in_w, t_out_w, t_ff1_w, t_ff2_w,
      ca_in_w, ca_out_w, ca_lin_w, wb);

  // ---- ODE (RK4), rk+states+zero fused into ode2 epilogues ----
  delta_kernel<<<ROWS1*DM/256, 256, 0, stream>>>(x, ts, deltab, delta16, dtrow, srcrow);
  RkArgs rk; rk.delta = deltab; rk.acc = accb; rk.y16 = y16;
  rk.dtrow = dtrow; rk.srcrow = srcrow; rk.x = x; rk.hin16 = hin16;
  const unsigned short* yin16 = delta16;
  const float was[4] = {1.f, 2.f, 2.f, 1.f};
  const float cys[4] = {0.5f, 0.5f, 1.f, 0.f};
  for (int s4 = 0; s4 < 4; s4++) {
    launch_bgemm(2, 32, yin16, wb_ode1, ode_b1, nullptr, nullptr, t16, ROWS1, 512, 512, 512, stream);
    rk.wa = was[s4]; rk.cy = cys[s4];
    dim3 grid(512/32, (ROWS1+127)/128), blk(256);
    if (s4 == 0)
      bgemm_kernel<0,32,1><<<grid,blk,0,stream>>>(t16, wb_ode2, ode_b2, nullptr, nullptr, nullptr, ROWS1, 512, 512, 512, rk);
    else if (s4 < 3)
      bgemm_kernel<0,32,2><<<grid,blk,0,stream>>>(t16, wb_ode2, ode_b2, nullptr, nullptr, nullptr, ROWS1, 512, 512, 512, rk);
    else
      bgemm_kernel<0,32,3><<<grid,blk,0,stream>>>(t16, wb_ode2, ode_b2, nullptr, nullptr, nullptr, ROWS1, 512, 512, 512, rk);
    yin16 = y16;
  }

  // ---- GRU ----
  launch_bgemm(0, 128, hin16, wb_gwih, gru_bih, nullptr, gx, nullptr, ROWS, 1536, 512, 1536, stream);
  gru_scan_kernel<<<GRU_BLK, 256, 0, stream>>>(gx, gru_whh, gru_bhh, hsb, hs16, hbuf);

  // ---- transformer (2 layers, pre-norm, causal); timeenc fused into l0 ln1 ----
  for (int l = 0; l < 2; l++) {
    if (l == 0)
      ln_kernel<1,1><<<ROWS,256,0,stream>>>(x, t_ln1_w, t_ln1_b, ln16, ts, te_a, te_b, zbuf);
    else
      ln_kernel<1,0><<<ROWS,256,0,stream>>>(zbuf, t_ln1_w + 512, t_ln1_b + 512, ln16,
                                            nullptr, nullptr, nullptr, nullptr);
    launch_bgemm(0, 128, ln16, wb_tin + (size_t)l*1536*512, t_in_b + l*1536, nullptr, nullptr, qkv16, ROWS, 1536, 512, 1536, stream);
    mattn_kernel<1><<<dim3(64, TT/64), 256, 0, stream>>>(qkv16, ao16);
    launch_bgemm(0, 32, ao16, wb_tout + (size_t)l*512*512, t_out_b + l*512, zbuf, zbuf, nullptr, ROWS, 512, 512, 512, stream);
    ln_kernel<1,0><<<ROWS,256,0,stream>>>(zbuf, t_ln2_w + l*512, t_ln2_b + l*512, ln16,
                                          nullptr, nullptr, nullptr, nullptr);
    launch_bgemm(1, 128, ln16, wb_ff1 + (size_t)l*2048*512, t_ff1_b + l*2048, nullptr, nullptr, ff1b16, ROWS, 2048, 512, 2048, stream);
    launch_bgemm(0, 32, ff1b16, wb_ff2 + (size_t)l*512*2048, t_ff2_b + l*512, zbuf, zbuf, nullptr, ROWS, 512, 2048, 512, stream);
  }
  ln_kernel<1,0><<<ROWS,256,0,stream>>>(zbuf, t_lnf_w, t_lnf_b, ln16,
                                        nullptr, nullptr, nullptr, nullptr);

  // ---- cross attention ----
  launch_bgemm(0, 32,  hs16, wb_cain,           ca_in_b,       nullptr, nullptr, qkv16,       ROWS,  512, 512, 1536, stream);
  launch_bgemm(0, 128, ln16, wb_cain + 512*512, ca_in_b + 512, nullptr, nullptr, qkv16 + 512, ROWS, 1024, 512, 1536, stream);
  mattn_kernel<0><<<dim3(64, TT/64), 256, 0, stream>>>(qkv16, ao16);
  launch_bgemm(0, 32, ao16, wb_caout, ca_out_b, nullptr, nullptr, cao16, ROWS, 512, 512, 512, stream);
  launch_bgemm(0, 32, cao16, wb_calin, ca_lin_b, hsb, fcur, nullptr, ROWS, 512, 512, 512, stream);
  ln_kernel<0,0><<<ROWS,256,0,stream>>>(fcur, ca_ln_w, ca_ln_b, (float*)d_out,
                                        nullptr, nullptr, nullptr, nullptr);
}

// Round 14
// 2705.745 us; speedup vs baseline: 2.3567x; 1.0033x over previous
//
#include <hip/hip_runtime.h>
#include <math.h>

#define BB 8
#define TT 1024
#define DM 512
#define ROWS (BB*TT)     // 8192
#define ROWS1 (BB*(TT-1))// 8184
#define GRU_J 16         // hidden dims per block
#define GRU_GPB 32       // blocks per batch
#define GRU_BLK (BB*GRU_GPB)  // 256 blocks = 1/CU

typedef __attribute__((ext_vector_type(4))) float f32x4;
typedef __attribute__((ext_vector_type(8))) short bf16x8;
typedef __attribute__((ext_vector_type(4))) short bf16x4;

#define GLOAD16(g, l) __builtin_amdgcn_global_load_lds( \
    (const __attribute__((address_space(1))) void*)(g), \
    (__attribute__((address_space(3))) void*)(l), 16, 0, 0)

struct RkArgs {
  const float* delta; float* acc; unsigned short* y16;
  const float* dtrow; const int* srcrow;
  const float* x; unsigned short* hin16;
  float wa, cy;
};

__device__ __forceinline__ float sigm_(float v){ return 1.f/(1.f+expf(-v)); }

__device__ __forceinline__ unsigned short f2bf(float f){
  unsigned u = __float_as_uint(f);
  return (unsigned short)((u + 0x7FFFu + ((u>>16)&1u)) >> 16);
}

// ---------------- fused weight cast (all 10 weights, 1 launch) ----------------
__global__ __launch_bounds__(256) void castall_kernel(
    const float* w0, const float* w1, const float* w2, const float* w3,
    const float* w4, const float* w5, const float* w6, const float* w7,
    const float* w8, const float* w9, unsigned short* __restrict__ o)
{
  int i = blockIdx.x*256 + threadIdx.x;           // in float4 units
  if (i >= 2228224) return;
  const float* src; int off;
  if      (i <   65536){ src=w0; off=0; }
  else if (i <  131072){ src=w1; off=65536; }
  else if (i <  327680){ src=w2; off=131072; }
  else if (i <  720896){ src=w3; off=327680; }
  else if (i <  851968){ src=w4; off=720896; }
  else if (i < 1376256){ src=w5; off=851968; }
  else if (i < 1900544){ src=w6; off=1376256; }
  else if (i < 2097152){ src=w7; off=1900544; }
  else if (i < 2162688){ src=w8; off=2097152; }
  else                 { src=w9; off=2162688; }
  float4 v = ((const float4*)src)[i - off];
  ushort4 u;
  u.x = f2bf(v.x); u.y = f2bf(v.y); u.z = f2bf(v.z); u.w = f2bf(v.w);
  ((ushort4*)o)[i] = u;
}

// ---------------- elementwise ----------------
__global__ __launch_bounds__(256) void delta_kernel(const float* __restrict__ x,
    const float* __restrict__ ts, float* __restrict__ delta,
    unsigned short* __restrict__ delta16,
    float* __restrict__ dtrow, int* __restrict__ srcrow)
{
  size_t i = (size_t)blockIdx.x*256 + threadIdx.x;
  int d = (int)(i & (DM-1));
  int r = (int)(i >> 9);
  int b = r / (TT-1), ii = r % (TT-1);
  float dt = ts[b*TT+ii+1] - ts[b*TT+ii];
  float x1 = x[((size_t)b*TT+ii+1)*DM + d];
  float x0 = x[((size_t)b*TT+ii)*DM + d];
  float v = (x1 - x0) / dt;
  delta[i] = v;
  delta16[i] = f2bf(v);
  if (d == 0) { dtrow[r] = dt; srcrow[r] = b*TT + ii; }
}

// ---------------- LayerNorm (block per row, D=512) ----------------
// TE=1: input = x + time-encoding (fused timeenc, layer-0 ln1); also writes zout f32.
template<int BF, int TE>
__global__ __launch_bounds__(256) void ln_kernel(const float* __restrict__ x,
    const float* __restrict__ w, const float* __restrict__ b,
    void* __restrict__ outp,
    const float* ts, const float* te_a, const float* te_b, float* zout)
{
  int row = blockIdx.x;
  int tid = threadIdx.x;
  const float* xr = x + (size_t)row*DM;
  float2 v = *(const float2*)(xr + tid*2);
  if (TE) {
    float t = ts[row];
    int d0 = tid*2;
    int fi = d0 >> 2;
    float fr = expf(-(float)fi * 0.061606661f) * 1.5707964f;
    float ph = t * fr;
    float tm0 = ((d0 & 3) == 0) ? sinf(ph) : cosf(ph);
    float tm1 = t*te_a[tid] + te_b[tid];
    v.x += tm0; v.y += tm1;
    *(float2*)(zout + (size_t)row*DM + tid*2) = v;
  }
  float s = v.x+v.y, sq = v.x*v.x + v.y*v.y;
  #pragma unroll
  for (int off=1; off<64; off<<=1){ s += __shfl_xor(s,off); sq += __shfl_xor(sq,off); }
  __shared__ float rs[4], rq[4];
  int wid = tid>>6;
  if ((tid&63)==0){ rs[wid]=s; rq[wid]=sq; }
  __syncthreads();
  s = rs[0]+rs[1]+rs[2]+rs[3];
  sq = rq[0]+rq[1]+rq[2]+rq[3];
  float mean = s*(1.f/DM);
  float var = sq*(1.f/DM) - mean*mean;
  float inv = rsqrtf(var + 1e-5f);
  float2 wv = *(const float2*)(w + tid*2);
  float2 bv = *(const float2*)(b + tid*2);
  float ox = (v.x-mean)*inv*wv.x + bv.x;
  float oy = (v.y-mean)*inv*wv.y + bv.y;
  if (BF) {
    ushort2 u; u.x = f2bf(ox); u.y = f2bf(oy);
    *(ushort2*)((unsigned short*)outp + (size_t)row*DM + tid*2) = u;
  } else {
    float2 o; o.x = ox; o.y = oy;
    *(float2*)((float*)outp + (size_t)row*DM + tid*2) = o;
  }
}

// ---------------- bf16 MFMA GEMM, global_load_lds staging ----------------
// TN 128/64/32. TN=32 -> grid N/32 (4 blocks/CU at N=512: latency hiding for
// the thin-N GEMMs). RKM: 0 none, 1 RK-init, 2 RK-mid, 3 RK-final (ldc==512).
template<int ACT, int TN, int RKM>
__global__ __launch_bounds__(256) void bgemm_kernel(
    const unsigned short* __restrict__ A16, const unsigned short* __restrict__ Wb,
    const float* __restrict__ bias, const float* res,
    float* C, unsigned short* Cb, int M, int N, int K, int ldc, RkArgs rk)
{
  const int NJ = (TN+31)/32;
  __shared__ __align__(16) unsigned short Al[2][128*32];
  __shared__ __align__(16) unsigned short Wl[2][TN*32];
  const int bm = blockIdx.y*128, bn = blockIdx.x*TN;
  const int tid = threadIdx.x;
  const int lane = tid & 63, wv = tid >> 6;
  const int wm = (wv&1)*64, wn = (wv>>1)*(TN/2);
  const int fl = lane & 15, fk = (lane>>4)*8;
  const int srw = lane >> 2;         // row within 16-row group
  const int scl = (lane & 3)*8;      // 16B slot (elems)
  f32x4 acc[4][NJ];
  #pragma unroll
  for (int i=0;i<4;i++)
    #pragma unroll
    for (int j=0;j<NJ;j++) acc[i][j] = (f32x4){0.f,0.f,0.f,0.f};

  const int nk = K >> 5;

  auto stage = [&](int buf, int kt){
    int k0 = kt*32;
    #pragma unroll
    for (int j=0;j<2;j++){
      int r = wv*32 + j*16 + srw;
      GLOAD16(A16 + (size_t)(bm + r)*K + k0 + scl,
              &Al[buf][(wv*32 + j*16)*32]);
    }
    if (TN == 128) {
      #pragma unroll
      for (int j=0;j<2;j++){
        int r = wv*32 + j*16 + srw;
        GLOAD16(Wb + (size_t)(bn + r)*K + k0 + scl,
                &Wl[buf][(wv*32 + j*16)*32]);
      }
    } else if (TN == 64) {
      int r = wv*16 + srw;
      GLOAD16(Wb + (size_t)(bn + r)*K + k0 + scl,
              &Wl[buf][(wv*16)*32]);
    } else {                       // TN==32: only waves 0-1 stage W
      if (wv < 2) {
        int r = wv*16 + srw;
        GLOAD16(Wb + (size_t)(bn + r)*K + k0 + scl,
                &Wl[buf][(wv*16)*32]);
      }
    }
  };

  stage(0, 0);
  int buf = 0;
  for (int kt = 0; kt < nk; ++kt) {
    __syncthreads();                 // drains vmcnt -> buf ready
    if (kt+1 < nk) stage(buf^1, kt+1);
    bf16x8 av[4], wvv[NJ];
    #pragma unroll
    for (int i=0;i<4;i++) av[i] = *(const bf16x8*)&Al[buf][(wm + i*16 + fl)*32 + fk];
    #pragma unroll
    for (int j=0;j<NJ;j++) wvv[j] = *(const bf16x8*)&Wl[buf][(wn + j*16 + fl)*32 + fk];
    #pragma unroll
    for (int i=0;i<4;i++)
      #pragma unroll
      for (int j=0;j<NJ;j++)
        acc[i][j] = __builtin_amdgcn_mfma_f32_16x16x32_bf16(av[i], wvv[j], acc[i][j], 0, 0, 0);
    buf ^= 1;
  }

  // epilogue: C/D layout col=lane&15, row=(lane>>4)*4+reg
  #pragma unroll
  for (int j=0;j<NJ;j++){
    int gn = bn + wn + j*16 + fl;
    float bv = bias[gn];
    #pragma unroll
    for (int i=0;i<4;i++){
      #pragma unroll
      for (int r=0;r<4;r++){
        int gm = bm + wm + i*16 + (lane>>4)*4 + r;
        if (gm >= M) continue;
        float v = acc[i][j][r] + bv;
        if (ACT==1) v = fmaxf(v, 0.f);
        if (ACT==2) v = tanhf(v);
        if (RKM == 0) {
          if (res) v += res[(size_t)gm*ldc + gn];
          if (C)  C[(size_t)gm*ldc + gn] = v;
          if (Cb) Cb[(size_t)gm*ldc + gn] = f2bf(v);
        } else {
          size_t idx = (size_t)gm*512 + gn;
          float dt = rk.dtrow[gm];
          if (RKM == 1) {
            rk.acc[idx] = v;
            rk.y16[idx] = f2bf(rk.delta[idx] + rk.cy*dt*v);
          } else if (RKM == 2) {
            rk.acc[idx] += rk.wa*v;
            rk.y16[idx] = f2bf(rk.delta[idx] + rk.cy*dt*v);
          } else {
            float a = rk.acc[idx] + v;
            int srow = rk.srcrow[gm];
            rk.hin16[((size_t)srow+1)*512 + gn] =
                f2bf(rk.x[(size_t)srow*512 + gn] + dt*(1.f/6.f)*a);
            if ((srow & (TT-1)) == 0)            // fused zero of t=0 row (after-RK safe)
              rk.hin16[(size_t)srow*512 + gn] = 0;
          }
        }
      }
    }
  }
}

// ---------------- MFMA flash attention ----------------
template<int CAUSAL>
__global__ __launch_bounds__(256) void mattn_kernel(
    const unsigned short* __restrict__ QKV, unsigned short* __restrict__ O)
{
  __shared__ __align__(16) unsigned short Kl[32][72];
  __shared__ __align__(16) unsigned short Vt[64][36];
  __shared__ __align__(16) unsigned short Pl[4][16][40];
  const int b = blockIdx.x >> 3, h = blockIdx.x & 7;
  const int q0 = blockIdx.y * 64;
  const int tid = threadIdx.x;
  const int lane = tid & 63, wid = tid >> 6;
  const int lq = lane & 15, g = lane >> 4;
  const size_t rowbase = (size_t)b*TT;

  bf16x8 qf0, qf1;
  {
    const unsigned short* qp = QKV + (rowbase + q0 + wid*16 + lq)*1536 + h*64 + g*8;
    qf0 = *(const bf16x8*)qp;
    qf1 = *(const bf16x8*)(qp + 32);
  }
  f32x4 o[4];
  #pragma unroll
  for (int dt=0; dt<4; dt++) o[dt] = (f32x4){0.f,0.f,0.f,0.f};
  float mr[4] = {-1e30f,-1e30f,-1e30f,-1e30f};
  float Lr[4] = {0.f,0.f,0.f,0.f};

  const int nkt = CAUSAL ? (q0/32 + 2) : (TT/32);
  const int qwmax = q0 + wid*16 + 15;
  const int sr = tid >> 3, scol = (tid & 7) * 8;

  for (int kt = 0; kt < nkt; ++kt) {
    const int k0 = kt*32;
    __syncthreads();
    *(uint4*)&Kl[sr][scol] = *(const uint4*)(QKV + (rowbase + k0 + sr)*1536 + 512 + h*64 + scol);
    {
      uint4 vv = *(const uint4*)(QKV + (rowbase + k0 + sr)*1536 + 1024 + h*64 + scol);
      const unsigned short* vs = (const unsigned short*)&vv;
      #pragma unroll
      for (int i=0;i<8;i++) Vt[scol+i][sr] = vs[i];
    }
    __syncthreads();
    if (CAUSAL && k0 > qwmax) continue;

    f32x4 st0 = (f32x4){0.f,0.f,0.f,0.f}, st1 = (f32x4){0.f,0.f,0.f,0.f};
    {
      bf16x8 kb;
      kb = *(const bf16x8*)&Kl[lq][g*8];
      st0 = __builtin_amdgcn_mfma_f32_16x16x32_bf16(qf0, kb, st0, 0,0,0);
      kb = *(const bf16x8*)&Kl[lq][g*8+32];
      st0 = __builtin_amdgcn_mfma_f32_16x16x32_bf16(qf1, kb, st0, 0,0,0);
      kb = *(const bf16x8*)&Kl[16+lq][g*8];
      st1 = __builtin_amdgcn_mfma_f32_16x16x32_bf16(qf0, kb, st1, 0,0,0);
      kb = *(const bf16x8*)&Kl[16+lq][g*8+32];
      st1 = __builtin_amdgcn_mfma_f32_16x16x32_bf16(qf1, kb, st1, 0,0,0);
    }
    float s0[4], s1[4];
    #pragma unroll
    for (int r=0;r<4;r++){ s0[r] = st0[r]*0.125f; s1[r] = st1[r]*0.125f; }
    if (CAUSAL) {
      int kg0 = k0 + lq, kg1 = k0 + 16 + lq;
      #pragma unroll
      for (int r=0;r<4;r++){
        int qg = q0 + wid*16 + 4*g + r;
        if (kg0 > qg) s0[r] = -1e30f;
        if (kg1 > qg) s1[r] = -1e30f;
      }
    }
    #pragma unroll
    for (int r=0;r<4;r++){
      float v = fmaxf(s0[r], s1[r]);
      v = fmaxf(v, __shfl_xor(v,1));
      v = fmaxf(v, __shfl_xor(v,2));
      v = fmaxf(v, __shfl_xor(v,4));
      v = fmaxf(v, __shfl_xor(v,8));
      float mn = fmaxf(mr[r], v);
      float scl = expf(mr[r] - mn);
      mr[r] = mn;
      float p0 = expf(s0[r] - mn);
      float p1 = expf(s1[r] - mn);
      float lt = p0 + p1;
      lt += __shfl_xor(lt,1); lt += __shfl_xor(lt,2);
      lt += __shfl_xor(lt,4); lt += __shfl_xor(lt,8);
      Lr[r] = Lr[r]*scl + lt;
      o[0][r] *= scl; o[1][r] *= scl; o[2][r] *= scl; o[3][r] *= scl;
      Pl[wid][4*g+r][lq]    = f2bf(p0);
      Pl[wid][4*g+r][16+lq] = f2bf(p1);
    }
    bf16x8 ap = *(const bf16x8*)&Pl[wid][lq][g*8];
    #pragma unroll
    for (int dt=0; dt<4; dt++){
      bf16x4 a4 = *(const bf16x4*)&Vt[lq+16*dt][g*8];
      bf16x4 b4 = *(const bf16x4*)&Vt[lq+16*dt][g*8+4];
      bf16x8 vb = __builtin_shufflevector(a4, b4, 0,1,2,3,4,5,6,7);
      o[dt] = __builtin_amdgcn_mfma_f32_16x16x32_bf16(ap, vb, o[dt], 0,0,0);
    }
  }

  #pragma unroll
  for (int r=0;r<4;r++){
    float inv = 1.f / Lr[r];
    int qg = q0 + wid*16 + 4*g + r;
    unsigned short* op = O + (rowbase + qg)*DM + h*64 + lq;
    op[0]  = f2bf(o[0][r]*inv);
    op[16] = f2bf(o[1][r]*inv);
    op[32] = f2bf(o[2][r]*inv);
    op[48] = f2bf(o[3][r]*inv);
  }
}

// ---------------- GRU scan v4.2: tagged-value sync, J=16, dbuf hsp ----------------
// FINAL: tagged words + relaxed agent atomics only. The R13 sc0 "XCD-local"
// fast path HUNG (per-CU L1 serves stale polls even within an XCD — G16).
// Agent-scope atomics are required for cross-CU visibility; this is the floor.
__global__ __launch_bounds__(256) void gru_scan_kernel(
    const float* __restrict__ gx,
    const float* __restrict__ whh,
    const float* __restrict__ bhh,
    float* __restrict__ Hs,
    unsigned short* __restrict__ Hsb,
    unsigned long long* hbuf)
{
  __shared__ float wlds[3][GRU_J][512];
  __shared__ float hsp[2][512];
  const int blk = blockIdx.x;
  const int b = blk & 7;           // batch -> XCD (round-robin dispatch)
  const int g = blk >> 3;          // slice 0..31
  const int j0 = g * GRU_J;
  const int tid = threadIdx.x;

  for (int idx = tid; idx < 3*GRU_J*512/4; idx += 256) {
    int f = idx*4;
    int gate = f >> 13;            // /(16*512)
    int rem = f & 8191;
    int jj = rem >> 9, k = rem & 511;
    *(float4*)&wlds[gate][jj][k] = *(const float4*)&whh[(size_t)(gate*512 + j0 + jj)*512 + k];
  }
  const int row = tid >> 4;        // dim 0..15 (16 lanes each)
  const int kl = tid & 15;
  const bool fin = (kl == 0);
  float bh0=0.f, bh1=0.f, bh2=0.f;
  if (fin) { bh0 = bhh[j0+row]; bh1 = bhh[512+j0+row]; bh2 = bhh[1024+j0+row]; }
  __syncthreads();

  for (int t = 0; t < TT; t++) {
    const int cur = t & 1;
    float g0=0.f, g1=0.f, g2=0.f;
    if (fin) {   // issued before poll; latency hides under the wait
      const float* gxr = gx + ((size_t)b*TT + t)*1536 + j0 + row;
      g0 = gxr[0]; g1 = gxr[512]; g2 = gxr[1024];
    }
    if (t == 0) {
      hsp[0][tid] = 0.f; hsp[0][tid+256] = 0.f;
    } else {
      const unsigned want = (unsigned)t;
      unsigned long long* src = hbuf + ((size_t)((t-1)&1)*BB + b)*512;
      unsigned long long u0, u1;
      for (;;) {
        u0 = __hip_atomic_load(src + tid,       __ATOMIC_RELAXED, __HIP_MEMORY_SCOPE_AGENT);
        u1 = __hip_atomic_load(src + tid + 256, __ATOMIC_RELAXED, __HIP_MEMORY_SCOPE_AGENT);
        if (((unsigned)(u0>>32) == want) & ((unsigned)(u1>>32) == want)) break;
        __builtin_amdgcn_s_sleep(1);
      }
      hsp[cur][tid]     = __uint_as_float((unsigned)u0);
      hsp[cur][tid+256] = __uint_as_float((unsigned)u1);
    }
    __syncthreads();   // hsp[cur] ready; next iter writes hsp[cur^1]

    float s0=0.f, s1=0.f, s2=0.f;
    #pragma unroll
    for (int j=0;j<8;j++){
      int k = kl*4 + j*64;
      float4 h4 = *(const float4*)&hsp[cur][k];
      float4 a = *(const float4*)&wlds[0][row][k];
      float4 c = *(const float4*)&wlds[1][row][k];
      float4 d = *(const float4*)&wlds[2][row][k];
      s0 += a.x*h4.x + a.y*h4.y + a.z*h4.z + a.w*h4.w;
      s1 += c.x*h4.x + c.y*h4.y + c.z*h4.z + c.w*h4.w;
      s2 += d.x*h4.x + d.y*h4.y + d.z*h4.z + d.w*h4.w;
    }
    #pragma unroll
    for (int off=1; off<16; off<<=1) {
      s0 += __shfl_xor(s0, off);
      s1 += __shfl_xor(s1, off);
      s2 += __shfl_xor(s2, off);
    }
    if (fin) {
      float r  = sigm_(g0 + s0 + bh0);
      float z  = sigm_(g1 + s1 + bh1);
      float n  = tanhf(g2 + r*(s2 + bh2));
      float hold = hsp[cur][j0 + row];
      float hnew = (1.f - z)*n + z*hold;
      size_t off = ((size_t)b*TT + t)*DM + j0 + row;
      Hs[off]  = hnew;
      Hsb[off] = f2bf(hnew);
      unsigned long long pk = ((unsigned long long)(unsigned)(t+1) << 32) | __float_as_uint(hnew);
      __hip_atomic_store(&hbuf[((size_t)cur*BB + b)*512 + j0 + row], pk,
                         __ATOMIC_RELAXED, __HIP_MEMORY_SCOPE_AGENT);
    }
  }
}

// ---------------- host ----------------
static RkArgs g_norm = {};

static void launch_bgemm(int act, int tn, const unsigned short* A16, const unsigned short* Wb,
                         const float* bias, const float* res, float* C, unsigned short* Cb,
                         int M, int N, int K, int ldc, hipStream_t stream)
{
  dim3 blk(256);
  if (tn == 128) {
    dim3 grid(N/128, (M+127)/128);
    switch(act){
      case 1: bgemm_kernel<1,128,0><<<grid,blk,0,stream>>>(A16,Wb,bias,res,C,Cb,M,N,K,ldc,g_norm); break;
      default: bgemm_kernel<0,128,0><<<grid,blk,0,stream>>>(A16,Wb,bias,res,C,Cb,M,N,K,ldc,g_norm); break;
    }
  } else {
    dim3 grid(N/32, (M+127)/128);
    switch(act){
      case 2: bgemm_kernel<2,32,0><<<grid,blk,0,stream>>>(A16,Wb,bias,res,C,Cb,M,N,K,ldc,g_norm); break;
      default: bgemm_kernel<0,32,0><<<grid,blk,0,stream>>>(A16,Wb,bias,res,C,Cb,M,N,K,ldc,g_norm); break;
    }
  }
}

extern "C" void kernel_launch(void* const* d_in, const int* in_sizes, int n_in,
                              void* d_out, int out_size, void* d_ws, size_t ws_size,
                              hipStream_t stream)
{
  (void)in_sizes; (void)n_in; (void)out_size; (void)ws_size;
  const float* x       = (const float*)d_in[0];
  const float* ts      = (const float*)d_in[1];
  const float* ode_w1  = (const float*)d_in[2];
  const float* ode_b1  = (const float*)d_in[3];
  const float* ode_w2  = (const float*)d_in[4];
  const float* ode_b2  = (const float*)d_in[5];
  const float* gru_wih = (const float*)d_in[6];
  const float* gru_whh = (const float*)d_in[7];
  const float* gru_bih = (const float*)d_in[8];
  const float* gru_bhh = (const float*)d_in[9];
  const float* te_a    = (const float*)d_in[10];
  const float* te_b    = (const float*)d_in[11];
  const float* t_in_w  = (const float*)d_in[12];
  const float* t_in_b  = (const float*)d_in[13];
  const float* t_out_w = (const float*)d_in[14];
  const float* t_out_b = (const float*)d_in[15];
  const float* t_ln1_w = (const float*)d_in[16];
  const float* t_ln1_b = (const float*)d_in[17];
  const float* t_ln2_w = (const float*)d_in[18];
  const float* t_ln2_b = (const float*)d_in[19];
  const float* t_ff1_w = (const float*)d_in[20];
  const float* t_ff1_b = (const float*)d_in[21];
  const float* t_ff2_w = (const float*)d_in[22];
  const float* t_ff2_b = (const float*)d_in[23];
  const float* t_lnf_w = (const float*)d_in[24];
  const float* t_lnf_b = (const float*)d_in[25];
  const float* ca_in_w = (const float*)d_in[26];
  const float* ca_in_b = (const float*)d_in[27];
  const float* ca_out_w= (const float*)d_in[28];
  const float* ca_out_b= (const float*)d_in[29];
  const float* ca_lin_w= (const float*)d_in[30];
  const float* ca_lin_b= (const float*)d_in[31];
  const float* ca_ln_w = (const float*)d_in[32];
  const float* ca_ln_b = (const float*)d_in[33];

  float* ws = (float*)d_ws;
  const size_t SZ = (size_t)ROWS * DM;
  // f32 pool
  float* deltab = ws + 0*SZ;
  float* accb   = ws + 1*SZ;
  float* fcur   = ws + 2*SZ;                 // ca pre-LN
  float* gx     = ws + 3*SZ;                 // 3*SZ
  float* zbuf   = ws + 6*SZ;
  float* hsb    = ws + 7*SZ;
  unsigned long long* hbuf = (unsigned long long*)(ws + 8*SZ);   // 64KB tagged
  float* dtrow  = ws + 8*SZ + 16384;                             // 8184 f32
  int*   srcrow = (int*)(ws + 8*SZ + 16384 + 8192);              // 8184 i32
  // bf16 pool
  unsigned short* u16 = (unsigned short*)(ws + 8*SZ + 16384 + 16384);
  unsigned short* delta16 = u16 + 0*SZ;
  unsigned short* y16     = u16 + 1*SZ;
  unsigned short* t16     = u16 + 2*SZ;
  unsigned short* hs16    = u16 + 3*SZ;
  unsigned short* ff1b16  = u16 + 4*SZ;      // 4*SZ; qkv16 aliases
  unsigned short* qkv16   = ff1b16;
  unsigned short* ao16    = delta16;
  unsigned short* hin16   = y16;
  unsigned short* cao16   = y16;
  unsigned short* ln16    = t16;
  // weights (one fused cast; offsets in elems = 4*float4-off)
  unsigned short* wb = u16 + 8*SZ;
  unsigned short* wb_ode1 = wb + 0;
  unsigned short* wb_ode2 = wb + 262144;
  unsigned short* wb_gwih = wb + 524288;
  unsigned short* wb_tin  = wb + 1310720;
  unsigned short* wb_tout = wb + 2883584;
  unsigned short* wb_ff1  = wb + 3407872;
  unsigned short* wb_ff2  = wb + 5505024;
  unsigned short* wb_cain = wb + 7602176;
  unsigned short* wb_caout= wb + 8388608;
  unsigned short* wb_calin= wb + 8650752;

  castall_kernel<<<(2228224+255)/256, 256, 0, stream>>>(
      ode_w1, ode_w2, gru_wih, t_in_w, t_out_w, t_ff1_w, t_ff2_w,
      ca_in_w, ca_out_w, ca_lin_w, wb);

  // ---- ODE (RK4), rk+states+zero fused into ode2 epilogues ----
  delta_kernel<<<ROWS1*DM/256, 256, 0, stream>>>(x, ts, deltab, delta16, dtrow, srcrow);
  RkArgs rk; rk.delta = deltab; rk.acc = accb; rk.y16 = y16;
  rk.dtrow = dtrow; rk.srcrow = srcrow; rk.x = x; rk.hin16 = hin16;
  const unsigned short* yin16 = delta16;
  const float was[4] = {1.f, 2.f, 2.f, 1.f};
  const float cys[4] = {0.5f, 0.5f, 1.f, 0.f};
  for (int s4 = 0; s4 < 4; s4++) {
    launch_bgemm(2, 32, yin16, wb_ode1, ode_b1, nullptr, nullptr, t16, ROWS1, 512, 512, 512, stream);
    rk.wa = was[s4]; rk.cy = cys[s4];
    dim3 grid(512/32, (ROWS1+127)/128), blk(256);
    if (s4 == 0)
      bgemm_kernel<0,32,1><<<grid,blk,0,stream>>>(t16, wb_ode2, ode_b2, nullptr, nullptr, nullptr, ROWS1, 512, 512, 512, rk);
    else if (s4 < 3)
      bgemm_kernel<0,32,2><<<grid,blk,0,stream>>>(t16, wb_ode2, ode_b2, nullptr, nullptr, nullptr, ROWS1, 512, 512, 512, rk);
    else
      bgemm_kernel<0,32,3><<<grid,blk,0,stream>>>(t16, wb_ode2, ode_b2, nullptr, nullptr, nullptr, ROWS1, 512, 512, 512, rk);
    yin16 = y16;
  }

  // ---- GRU ----
  launch_bgemm(0, 128, hin16, wb_gwih, gru_bih, nullptr, gx, nullptr, ROWS, 1536, 512, 1536, stream);
  gru_scan_kernel<<<GRU_BLK, 256, 0, stream>>>(gx, gru_whh, gru_bhh, hsb, hs16, hbuf);

  // ---- transformer (2 layers, pre-norm, causal); timeenc fused into l0 ln1 ----
  for (int l = 0; l < 2; l++) {
    if (l == 0)
      ln_kernel<1,1><<<ROWS,256,0,stream>>>(x, t_ln1_w, t_ln1_b, ln16, ts, te_a, te_b, zbuf);
    else
      ln_kernel<1,0><<<ROWS,256,0,stream>>>(zbuf, t_ln1_w + 512, t_ln1_b + 512, ln16,
                                            nullptr, nullptr, nullptr, nullptr);
    launch_bgemm(0, 128, ln16, wb_tin + (size_t)l*1536*512, t_in_b + l*1536, nullptr, nullptr, qkv16, ROWS, 1536, 512, 1536, stream);
    mattn_kernel<1><<<dim3(64, TT/64), 256, 0, stream>>>(qkv16, ao16);
    launch_bgemm(0, 32, ao16, wb_tout + (size_t)l*512*512, t_out_b + l*512, zbuf, zbuf, nullptr, ROWS, 512, 512, 512, stream);
    ln_kernel<1,0><<<ROWS,256,0,stream>>>(zbuf, t_ln2_w + l*512, t_ln2_b + l*512, ln16,
                                          nullptr, nullptr, nullptr, nullptr);
    launch_bgemm(1, 128, ln16, wb_ff1 + (size_t)l*2048*512, t_ff1_b + l*2048, nullptr, nullptr, ff1b16, ROWS, 2048, 512, 2048, stream);
    launch_bgemm(0, 32, ff1b16, wb_ff2 + (size_t)l*512*2048, t_ff2_b + l*512, zbuf, zbuf, nullptr, ROWS, 512, 2048, 512, stream);
  }
  ln_kernel<1,0><<<ROWS,256,0,stream>>>(zbuf, t_lnf_w, t_lnf_b, ln16,
                                        nullptr, nullptr, nullptr, nullptr);

  // ---- cross attention ----
  launch_bgemm(0, 32,  hs16, wb_cain,           ca_in_b,       nullptr, nullptr, qkv16,       ROWS,  512, 512, 1536, stream);
  launch_bgemm(0, 128, ln16, wb_cain + 512*512, ca_in_b + 512, nullptr, nullptr, qkv16 + 512, ROWS, 1024, 512, 1536, stream);
  mattn_kernel<0><<<dim3(64, TT/64), 256, 0, stream>>>(qkv16, ao16);
  launch_bgemm(0, 32, ao16, wb_caout, ca_out_b, nullptr, nullptr, cao16, ROWS, 512, 512, 512, stream);
  launch_bgemm(0, 32, cao16, wb_calin, ca_lin_b, hsb, fcur, nullptr, ROWS, 512, 512, 512, stream);
  ln_kernel<0,0><<<ROWS,256,0,stream>>>(fcur, ca_ln_w, ca_ln_b, (float*)d_out,
                                        nullptr, nullptr, nullptr, nullptr);
}